// Round 5
// baseline (1335.074 us; speedup 1.0000x reference)
//
#include <hip/hip_runtime.h>
#include <math.h>

#define NLAYER 6
#define DMODEL 768
#define NHEAD 12
#define DHEAD 64
#define FFDIM 3072
#define SEQ 512
#define BATCH 8
#define NTOK (BATCH * SEQ) /* 4096 */
#define ND ((size_t)NTOK * DMODEL)

typedef __bf16 bf16_t;
typedef __bf16 bf16x8 __attribute__((ext_vector_type(8)));
typedef float f32x4 __attribute__((ext_vector_type(4)));

__device__ __forceinline__ float bf2f(ushort u) {
    return __uint_as_float(((unsigned int)u) << 16);
}
union BFU { __bf16 h; ushort u; };
__device__ __forceinline__ ushort f2b(float x) { BFU c; c.h = (__bf16)x; return c.u; }

#define GLDS(gp, lp) __builtin_amdgcn_global_load_lds( \
    (const __attribute__((address_space(1))) void*)(gp), \
    (__attribute__((address_space(3))) void*)(lp), 16, 0, 0)

// ---------------------------------------------------------------------------
// bf16 MFMA GEMM, 64x128 tile, BK=32, 2-phase dbuf + XCD swizzle.
// R0-R4 established throughput ~ waves/CU (433 TF @12 waves, 300 @6);
// 64-row tile gives grid 1536 -> 6 blocks/CU -> 24 waves/CU.
// 4 waves 2x2, wave = 32x64 via acc[2][4]. act: 0 none, 1 exact gelu.
// Writes Cf (fp32) or Cb (bf16).  Used for FF1.
// ---------------------------------------------------------------------------
__global__ __launch_bounds__(256) void gemm_mfma(
    const ushort* __restrict__ A, const ushort* __restrict__ Bt,
    const float* __restrict__ bias, float* __restrict__ Cf,
    ushort* __restrict__ Cb, int M, int K, int N, int act)
{
    __shared__ __align__(16) ushort As[4096];   // 2 x (64x32)
    __shared__ __align__(16) ushort Bs[8192];   // 2 x (128x32)

    const int t = threadIdx.x;
    const int w = t >> 6, l = t & 63;
    const int wr = w >> 1, wc = w & 1;

    const int hw = blockIdx.x + gridDim.x * blockIdx.y;
    const int nwg = gridDim.x * gridDim.y;      // divisible by 8
    const int sw = (hw & 7) * (nwg >> 3) + (hw >> 3);
    const int bx = sw % gridDim.x, by = sw / gridDim.x;

    const int row0 = by * 64, col0 = bx * 128;

    f32x4 acc[2][4];
#pragma unroll
    for (int mi = 0; mi < 2; ++mi)
#pragma unroll
        for (int ni = 0; ni < 4; ++ni)
#pragma unroll
            for (int e = 0; e < 4; ++e) acc[mi][ni][e] = 0.f;

    const int rS = t >> 2, kg = (t & 3) ^ ((rS >> 1) & 3);
    const ushort* gA  = A  + (size_t)(row0 + rS) * K + kg * 8;
    const ushort* gB0 = Bt + (size_t)(col0 + rS) * K + kg * 8;
    const ushort* gB1 = Bt + (size_t)(col0 + 64 + rS) * K + kg * 8;

    const int lm = l & 15, lq = l >> 4;
    int aoff[2], boff[4];
#pragma unroll
    for (int mi = 0; mi < 2; ++mi) {
        int m = wr * 32 + mi * 16 + lm;
        aoff[mi] = m * 32 + (lq ^ ((m >> 1) & 3)) * 8;
    }
#pragma unroll
    for (int ni = 0; ni < 4; ++ni) {
        int n = wc * 64 + ni * 16 + lm;
        boff[ni] = n * 32 + (lq ^ ((n >> 1) & 3)) * 8;
    }

#define STAGE_FF(b, k0) do {                                  \
        GLDS(gA  + (k0), &As[(b) * 2048 + w * 512]);          \
        GLDS(gB0 + (k0), &Bs[(b) * 4096 + w * 512]);          \
        GLDS(gB1 + (k0), &Bs[(b) * 4096 + 2048 + w * 512]);   \
    } while (0)

#define COMPUTE_FF(b) do {                                                  \
        bf16x8 af[2], bfr[4];                                               \
        _Pragma("unroll")                                                   \
        for (int mi = 0; mi < 2; ++mi)                                      \
            af[mi] = *(const bf16x8*)&As[(b) * 2048 + aoff[mi]];            \
        _Pragma("unroll")                                                   \
        for (int ni = 0; ni < 4; ++ni)                                      \
            bfr[ni] = *(const bf16x8*)&Bs[(b) * 4096 + boff[ni]];           \
        _Pragma("unroll")                                                   \
        for (int mi = 0; mi < 2; ++mi)                                      \
            _Pragma("unroll")                                               \
            for (int ni = 0; ni < 4; ++ni)                                  \
                acc[mi][ni] = __builtin_amdgcn_mfma_f32_16x16x32_bf16(      \
                    af[mi], bfr[ni], acc[mi][ni], 0, 0, 0);                 \
    } while (0)

    const int nst = K >> 5;
    STAGE_FF(0, 0);
    __syncthreads();
    int cur = 0;
    for (int s = 0; s < nst - 1; ++s) {
        STAGE_FF(cur ^ 1, (s + 1) * 32);
        COMPUTE_FF(cur);
        __syncthreads();
        cur ^= 1;
    }
    COMPUTE_FF(cur);

#pragma unroll
    for (int mi = 0; mi < 2; ++mi) {
        int rowb = row0 + wr * 32 + mi * 16 + lq * 4;
#pragma unroll
        for (int ni = 0; ni < 4; ++ni) {
            int col = col0 + wc * 64 + ni * 16 + lm;
            float bv = bias[col];
#pragma unroll
            for (int r = 0; r < 4; ++r) {
                float v = acc[mi][ni][r] + bv;
                if (act == 1) v = 0.5f * v * (1.0f + erff(v * 0.70710678118654752f));
                size_t idx = (size_t)(rowb + r) * N + col;
                if (Cb) ((bf16_t*)Cb)[idx] = (bf16_t)v;
                else    Cf[idx] = v;
            }
        }
    }
#undef STAGE_FF
#undef COMPUTE_FF
}

// ---------------------------------------------------------------------------
// Split-K bf16 MFMA GEMM, 64x128 tile, up to 4 splits. 2-phase dbuf + XCD
// swizzle. z selects K-range and explicit partial dest P0..P3 (fixed-buffer
// scheme; aliasing of P1..P3 onto dead workspace is analyzed in launch).
// Bias folded into split 0.  Used for attn-out (nsplit=2) and FF2 (nsplit=4
// -> grid 1536 -> 6 blocks/CU -> 24 waves/CU).
// ---------------------------------------------------------------------------
__global__ __launch_bounds__(256) void gemm_mfma_sk(
    const ushort* __restrict__ A, const ushort* __restrict__ Bt,
    const float* __restrict__ bias, float* __restrict__ P0,
    float* __restrict__ P1, float* __restrict__ P2, float* __restrict__ P3,
    int M, int K, int N, int kLen)
{
    __shared__ __align__(16) ushort As[4096];   // 2 x (64x32)
    __shared__ __align__(16) ushort Bs[8192];   // 2 x (128x32)

    const int t = threadIdx.x;
    const int w = t >> 6, l = t & 63;
    const int wr = w >> 1, wc = w & 1;

    const int X = gridDim.x, XY = gridDim.x * gridDim.y;
    const int hw = blockIdx.x + X * blockIdx.y + XY * blockIdx.z;
    const int nwg = XY * gridDim.z;             // divisible by 8
    const int sw = (hw & 7) * (nwg >> 3) + (hw >> 3);
    const int z  = sw / XY;
    const int rr_ = sw - z * XY;
    const int bx = rr_ % X, by = rr_ / X;

    const int row0 = by * 64, col0 = bx * 128;
    const int kOff = z * kLen;
    float* Pz = (z == 0) ? P0 : (z == 1) ? P1 : (z == 2) ? P2 : P3;

    f32x4 acc[2][4];
#pragma unroll
    for (int mi = 0; mi < 2; ++mi)
#pragma unroll
        for (int ni = 0; ni < 4; ++ni)
#pragma unroll
            for (int e = 0; e < 4; ++e) acc[mi][ni][e] = 0.f;

    const int rS = t >> 2, kg = (t & 3) ^ ((rS >> 1) & 3);
    const ushort* gA  = A  + (size_t)(row0 + rS) * K + kg * 8;
    const ushort* gB0 = Bt + (size_t)(col0 + rS) * K + kg * 8;
    const ushort* gB1 = Bt + (size_t)(col0 + 64 + rS) * K + kg * 8;

    const int lm = l & 15, lq = l >> 4;
    int aoff[2], boff[4];
#pragma unroll
    for (int mi = 0; mi < 2; ++mi) {
        int m = wr * 32 + mi * 16 + lm;
        aoff[mi] = m * 32 + (lq ^ ((m >> 1) & 3)) * 8;
    }
#pragma unroll
    for (int ni = 0; ni < 4; ++ni) {
        int n = wc * 64 + ni * 16 + lm;
        boff[ni] = n * 32 + (lq ^ ((n >> 1) & 3)) * 8;
    }

#define STAGE_SK(b, k0) do {                                  \
        GLDS(gA  + (k0), &As[(b) * 2048 + w * 512]);          \
        GLDS(gB0 + (k0), &Bs[(b) * 4096 + w * 512]);          \
        GLDS(gB1 + (k0), &Bs[(b) * 4096 + 2048 + w * 512]);   \
    } while (0)

#define COMPUTE_SK(b) do {                                                  \
        bf16x8 af[2], bfr[4];                                               \
        _Pragma("unroll")                                                   \
        for (int mi = 0; mi < 2; ++mi)                                      \
            af[mi] = *(const bf16x8*)&As[(b) * 2048 + aoff[mi]];            \
        _Pragma("unroll")                                                   \
        for (int ni = 0; ni < 4; ++ni)                                      \
            bfr[ni] = *(const bf16x8*)&Bs[(b) * 4096 + boff[ni]];           \
        _Pragma("unroll")                                                   \
        for (int mi = 0; mi < 2; ++mi)                                      \
            _Pragma("unroll")                                               \
            for (int ni = 0; ni < 4; ++ni)                                  \
                acc[mi][ni] = __builtin_amdgcn_mfma_f32_16x16x32_bf16(      \
                    af[mi], bfr[ni], acc[mi][ni], 0, 0, 0);                 \
    } while (0)

    const int nst = kLen >> 5;
    STAGE_SK(0, kOff);
    __syncthreads();
    int cur = 0;
    for (int s = 0; s < nst - 1; ++s) {
        STAGE_SK(cur ^ 1, kOff + (s + 1) * 32);
        COMPUTE_SK(cur);
        __syncthreads();
        cur ^= 1;
    }
    COMPUTE_SK(cur);

#pragma unroll
    for (int mi = 0; mi < 2; ++mi) {
        int rowb = row0 + wr * 32 + mi * 16 + lq * 4;
#pragma unroll
        for (int ni = 0; ni < 4; ++ni) {
            int col = col0 + wc * 64 + ni * 16 + lm;
            float bv = (z == 0) ? bias[col] : 0.f;
#pragma unroll
            for (int r = 0; r < 4; ++r)
                Pz[(size_t)(rowb + r) * N + col] = acc[mi][ni][r] + bv;
        }
    }
#undef STAGE_SK
#undef COMPUTE_SK
}

// ---------------------------------------------------------------------------
// Fused QKV GEMM, 64x128 tile, 2-phase dbuf + XCD swizzle.
// A (M x 768) @ Wqkvt^T (2304 x 768) -> q (scaled, token-major bf16),
// k (token-major bf16), v (TRANSPOSED [b,h,d,s] bf16 for attn PV).
// ---------------------------------------------------------------------------
__global__ __launch_bounds__(256) void gemm_qkv(
    const ushort* __restrict__ A, const ushort* __restrict__ Bt,
    const float* __restrict__ bq, const float* __restrict__ bk,
    const float* __restrict__ bv,
    ushort* __restrict__ qb, ushort* __restrict__ kb, ushort* __restrict__ vtb)
{
    __shared__ __align__(16) ushort As[4096];   // 2 x (64x32)
    __shared__ __align__(16) ushort Bs[8192];   // 2 x (128x32)

    const int K = DMODEL;
    const int t = threadIdx.x;
    const int w = t >> 6, l = t & 63;
    const int wr = w >> 1, wc = w & 1;

    const int hw = blockIdx.x + 18 * blockIdx.y;    // grid (18,64) = 1152
    const int sw = (hw & 7) * 144 + (hw >> 3);
    const int bx = sw % 18, by = sw / 18;

    const int row0 = by * 64, col0 = bx * 128;
    const int seg = bx / 6;            // 0=q 1=k 2=v

    f32x4 acc[2][4];
#pragma unroll
    for (int mi = 0; mi < 2; ++mi)
#pragma unroll
        for (int ni = 0; ni < 4; ++ni)
#pragma unroll
            for (int e = 0; e < 4; ++e) acc[mi][ni][e] = 0.f;

    const int rS = t >> 2, kg = (t & 3) ^ ((rS >> 1) & 3);
    const ushort* gA  = A  + (size_t)(row0 + rS) * K + kg * 8;
    const ushort* gB0 = Bt + (size_t)(col0 + rS) * K + kg * 8;
    const ushort* gB1 = Bt + (size_t)(col0 + 64 + rS) * K + kg * 8;

    const int lm = l & 15, lq = l >> 4;
    int aoff[2], boff[4];
#pragma unroll
    for (int mi = 0; mi < 2; ++mi) {
        int m = wr * 32 + mi * 16 + lm;
        aoff[mi] = m * 32 + (lq ^ ((m >> 1) & 3)) * 8;
    }
#pragma unroll
    for (int ni = 0; ni < 4; ++ni) {
        int n = wc * 64 + ni * 16 + lm;
        boff[ni] = n * 32 + (lq ^ ((n >> 1) & 3)) * 8;
    }

#define STAGE_QKV(b, k0) do {                                 \
        GLDS(gA  + (k0), &As[(b) * 2048 + w * 512]);          \
        GLDS(gB0 + (k0), &Bs[(b) * 4096 + w * 512]);          \
        GLDS(gB1 + (k0), &Bs[(b) * 4096 + 2048 + w * 512]);   \
    } while (0)

#define COMPUTE_QKV(b) do {                                                 \
        bf16x8 af[2], bfr[4];                                               \
        _Pragma("unroll")                                                   \
        for (int mi = 0; mi < 2; ++mi)                                      \
            af[mi] = *(const bf16x8*)&As[(b) * 2048 + aoff[mi]];            \
        _Pragma("unroll")                                                   \
        for (int ni = 0; ni < 4; ++ni)                                      \
            bfr[ni] = *(const bf16x8*)&Bs[(b) * 4096 + boff[ni]];           \
        _Pragma("unroll")                                                   \
        for (int mi = 0; mi < 2; ++mi)                                      \
            _Pragma("unroll")                                               \
            for (int ni = 0; ni < 4; ++ni)                                  \
                acc[mi][ni] = __builtin_amdgcn_mfma_f32_16x16x32_bf16(      \
                    af[mi], bfr[ni], acc[mi][ni], 0, 0, 0);                 \
    } while (0)

    const int nst = K >> 5;   // 24
    STAGE_QKV(0, 0);
    __syncthreads();
    int cur = 0;
    for (int s = 0; s < nst - 1; ++s) {
        STAGE_QKV(cur ^ 1, (s + 1) * 32);
        COMPUTE_QKV(cur);
        __syncthreads();
        cur ^= 1;
    }
    COMPUTE_QKV(cur);

    const float* bp = (seg == 0) ? bq : (seg == 1) ? bk : bv;
    const float sc = (seg == 0) ? 0.125f : 1.0f;
#pragma unroll
    for (int mi = 0; mi < 2; ++mi) {
        int rowb = row0 + wr * 32 + mi * 16 + lq * 4;
#pragma unroll
        for (int ni = 0; ni < 4; ++ni) {
            int col = col0 + wc * 64 + ni * 16 + lm;
            int lcol = col - seg * 768;
            float bvv = bp[lcol];
            if (seg == 2) {
                int hh = lcol >> 6, dd = lcol & 63;
                int bb = rowb >> 9, ss = rowb & 511;
                ushort4 o;
                o.x = f2b(acc[mi][ni][0] + bvv);
                o.y = f2b(acc[mi][ni][1] + bvv);
                o.z = f2b(acc[mi][ni][2] + bvv);
                o.w = f2b(acc[mi][ni][3] + bvv);
                *(ushort4*)&vtb[(((size_t)(bb * NHEAD + hh)) * DHEAD + dd) * SEQ + ss] = o;
            } else {
                ushort* dst = seg ? kb : qb;
#pragma unroll
                for (int r = 0; r < 4; ++r)
                    dst[(size_t)(rowb + r) * DMODEL + lcol] = f2b((acc[mi][ni][r] + bvv) * sc);
            }
        }
    }
#undef STAGE_QKV
#undef COMPUTE_QKV
}

// ---------------------------------------------------------------------------
// MFMA flash attention (unchanged).
// ---------------------------------------------------------------------------
#define QSTR 72

__global__ __launch_bounds__(256) void attn_mfma(
    const ushort* __restrict__ qb, const ushort* __restrict__ kb,
    const ushort* __restrict__ vtb, const int* __restrict__ mask,
    ushort* __restrict__ ctxb)
{
    __shared__ __align__(16) ushort Qs[64 * QSTR];
    __shared__ __align__(16) ushort Ks[64 * QSTR];
    __shared__ __align__(16) ushort Vs[64 * QSTR];
    __shared__ __align__(16) ushort Ps[64 * QSTR];
    __shared__ float Ma[64];

    const int qt = blockIdx.x, h = blockIdx.y, b = blockIdx.z;
    const int t = threadIdx.x;
    const int w = t >> 6, l = t & 63;
    const int lm = l & 15, lq = l >> 4;

#pragma unroll
    for (int i = 0; i < 2; ++i) {
        int ch = t + i * 256;
        int r = ch >> 3, c8 = ch & 7;
        *(uint4*)&Qs[r * QSTR + c8 * 8] =
            *(const uint4*)&qb[((size_t)(b * SEQ + qt * 64 + r)) * DMODEL + h * DHEAD + c8 * 8];
    }

    f32x4 O[4];
#pragma unroll
    for (int n0 = 0; n0 < 4; ++n0)
#pragma unroll
        for (int e = 0; e < 4; ++e) O[n0][e] = 0.f;
    float mrow[4] = {-3.4e38f, -3.4e38f, -3.4e38f, -3.4e38f};
    float lrow[4] = {0.f, 0.f, 0.f, 0.f};

    const int qrow = w * 16 + lm;
    const int prow = w * 16 + lq * 4;

    for (int kt = 0; kt < SEQ / 64; ++kt) {
#pragma unroll
        for (int i = 0; i < 2; ++i) {
            int ch = t + i * 256;
            int r = ch >> 3, c8 = ch & 7;
            *(uint4*)&Ks[r * QSTR + c8 * 8] =
                *(const uint4*)&kb[((size_t)(b * SEQ + kt * 64 + r)) * DMODEL + h * DHEAD + c8 * 8];
            *(uint4*)&Vs[r * QSTR + c8 * 8] =
                *(const uint4*)&vtb[(((size_t)(b * NHEAD + h)) * DHEAD + r) * SEQ + kt * 64 + c8 * 8];
        }
        if (t < 64) Ma[t] = (mask[b * SEQ + kt * 64 + t] == 0) ? -1e9f : 0.f;
        __syncthreads();

        bf16x8 aq0 = *(const bf16x8*)&Qs[qrow * QSTR + lq * 8];
        bf16x8 aq1 = *(const bf16x8*)&Qs[qrow * QSTR + lq * 8 + 32];
        f32x4 S[4];
#pragma unroll
        for (int n0 = 0; n0 < 4; ++n0) {
#pragma unroll
            for (int e = 0; e < 4; ++e) S[n0][e] = 0.f;
            bf16x8 b0 = *(const bf16x8*)&Ks[(n0 * 16 + lm) * QSTR + lq * 8];
            bf16x8 b1 = *(const bf16x8*)&Ks[(n0 * 16 + lm) * QSTR + lq * 8 + 32];
            S[n0] = __builtin_amdgcn_mfma_f32_16x16x32_bf16(aq0, b0, S[n0], 0, 0, 0);
            S[n0] = __builtin_amdgcn_mfma_f32_16x16x32_bf16(aq1, b1, S[n0], 0, 0, 0);
        }

        float ma4[4];
#pragma unroll
        for (int n0 = 0; n0 < 4; ++n0) ma4[n0] = Ma[n0 * 16 + lm];
#pragma unroll
        for (int n0 = 0; n0 < 4; ++n0)
#pragma unroll
            for (int r = 0; r < 4; ++r) S[n0][r] += ma4[n0];

        float tm[4];
#pragma unroll
        for (int r = 0; r < 4; ++r)
            tm[r] = fmaxf(fmaxf(S[0][r], S[1][r]), fmaxf(S[2][r], S[3][r]));
#pragma unroll
        for (int off = 1; off < 16; off <<= 1)
#pragma unroll
            for (int r = 0; r < 4; ++r)
                tm[r] = fmaxf(tm[r], __shfl_xor(tm[r], off, 64));

        float al[4], ts[4];
#pragma unroll
        for (int r = 0; r < 4; ++r) {
            float mn = fmaxf(mrow[r], tm[r]);
            al[r] = __expf(mrow[r] - mn);
            mrow[r] = mn;
            ts[r] = 0.f;
        }
#pragma unroll
        for (int n0 = 0; n0 < 4; ++n0)
#pragma unroll
            for (int r = 0; r < 4; ++r) {
                float p = __expf(S[n0][r] - mrow[r]);
                ts[r] += p;
                Ps[(prow + r) * QSTR + n0 * 16 + lm] = f2b(p);
            }
#pragma unroll
        for (int off = 1; off < 16; off <<= 1)
#pragma unroll
            for (int r = 0; r < 4; ++r)
                ts[r] += __shfl_xor(ts[r], off, 64);
#pragma unroll
        for (int r = 0; r < 4; ++r) lrow[r] = lrow[r] * al[r] + ts[r];
#pragma unroll
        for (int n0 = 0; n0 < 4; ++n0)
#pragma unroll
            for (int r = 0; r < 4; ++r) O[n0][r] *= al[r];

        bf16x8 ap0 = *(const bf16x8*)&Ps[qrow * QSTR + lq * 8];
        bf16x8 ap1 = *(const bf16x8*)&Ps[qrow * QSTR + lq * 8 + 32];
#pragma unroll
        for (int n0 = 0; n0 < 4; ++n0) {
            bf16x8 v0 = *(const bf16x8*)&Vs[(n0 * 16 + lm) * QSTR + lq * 8];
            bf16x8 v1 = *(const bf16x8*)&Vs[(n0 * 16 + lm) * QSTR + lq * 8 + 32];
            O[n0] = __builtin_amdgcn_mfma_f32_16x16x32_bf16(ap0, v0, O[n0], 0, 0, 0);
            O[n0] = __builtin_amdgcn_mfma_f32_16x16x32_bf16(ap1, v1, O[n0], 0, 0, 0);
        }
        __syncthreads();
    }

    float inv[4];
#pragma unroll
    for (int r = 0; r < 4; ++r) inv[r] = 1.f / lrow[r];
#pragma unroll
    for (int n0 = 0; n0 < 4; ++n0)
#pragma unroll
        for (int r = 0; r < 4; ++r)
            Ks[(prow + r) * QSTR + n0 * 16 + lm] = f2b(O[n0][r] * inv[r]);
    __syncthreads();
#pragma unroll
    for (int i = 0; i < 2; ++i) {
        int ch = t + i * 256;
        int r = ch >> 3, c8 = ch & 7;
        *(uint4*)&ctxb[((size_t)(b * SEQ + qt * 64 + r)) * DMODEL + h * DHEAD + c8 * 8] =
            *(const uint4*)&Ks[r * QSTR + c8 * 8];
    }
}

// ---------------------------------------------------------------------------
// Per-layer weight transpose+convert: K x N fp32 -> N x K bf16.
// ---------------------------------------------------------------------------
__global__ __launch_bounds__(256) void transpose_w(
    const float* __restrict__ Wq, const float* __restrict__ Wk,
    const float* __restrict__ Wv, const float* __restrict__ Wo,
    const float* __restrict__ W1, const float* __restrict__ W2,
    ushort* __restrict__ Wqt, ushort* __restrict__ Wkt,
    ushort* __restrict__ Wvt, ushort* __restrict__ Wot,
    ushort* __restrict__ W1t, ushort* __restrict__ W2t)
{
    __shared__ float tile[32][33];
    const int bid = blockIdx.x;
    const float* src; ushort* dst; int K, N, tx, ty;
    if (bid < 2304) {
        int m = bid / 576, tl = bid % 576;
        src = (m == 0) ? Wq : (m == 1) ? Wk : (m == 2) ? Wv : Wo;
        dst = (m == 0) ? Wqt : (m == 1) ? Wkt : (m == 2) ? Wvt : Wot;
        K = 768; N = 768; tx = tl % 24; ty = tl / 24;
    } else if (bid < 4608) {
        int tl = bid - 2304;
        src = W1; dst = W1t; K = 768; N = 3072; tx = tl % 96; ty = tl / 96;
    } else {
        int tl = bid - 4608;
        src = W2; dst = W2t; K = 3072; N = 768; tx = tl % 24; ty = tl / 24;
    }
    const int t = threadIdx.x;
    const int lx = t & 31, ly = t >> 5;
    const int n0 = tx * 32, k0 = ty * 32;
#pragma unroll
    for (int i = 0; i < 4; ++i)
        tile[lx][ly + i * 8] = src[(size_t)(k0 + ly + i * 8) * N + n0 + lx];
    __syncthreads();
#pragma unroll
    for (int i = 0; i < 4; ++i)
        ((bf16_t*)dst)[(size_t)(n0 + ly + i * 8) * K + k0 + lx] =
            (bf16_t)tile[ly + i * 8][lx];
}

// ---------------------------------------------------------------------------
__global__ __launch_bounds__(256) void f2bf_kernel(
    const float* __restrict__ src, ushort* __restrict__ dst)
{
    const size_t i = ((size_t)blockIdx.x * 256 + threadIdx.x) * 4;
    float4 v = *(const float4*)(src + i);
    ushort4 o;
    o.x = f2b(v.x); o.y = f2b(v.y); o.z = f2b(v.z); o.w = f2b(v.w);
    *(ushort4*)(dst + i) = o;
}

// ---------------------------------------------------------------------------
// out = LayerNorm(p0 + p1 + res); fp32 out + bf16 shadow.  (LN1)
// ---------------------------------------------------------------------------
__global__ __launch_bounds__(256) void add_ln3_kernel(
    const float* __restrict__ p0, const float* __restrict__ p1,
    const float* __restrict__ res,
    const float* __restrict__ gw, const float* __restrict__ bw,
    float* __restrict__ out, ushort* __restrict__ outb)
{
    const int row = blockIdx.x;
    const int t = threadIdx.x;
    __shared__ float red[8];

    const float* a0 = p0 + (size_t)row * DMODEL;
    const float* a1 = p1 + (size_t)row * DMODEL;
    const float* rr = res + (size_t)row * DMODEL;

    float vals[3];
    float s = 0.f;
#pragma unroll
    for (int i = 0; i < 3; ++i) {
        int c = t + i * 256;
        vals[i] = a0[c] + a1[c] + rr[c];
        s += vals[i];
    }
#pragma unroll
    for (int off = 32; off > 0; off >>= 1) s += __shfl_down(s, off, 64);
    if ((t & 63) == 0) red[t >> 6] = s;
    __syncthreads();
    const float mu = (red[0] + red[1] + red[2] + red[3]) * (1.0f / DMODEL);

    float vs = 0.f;
#pragma unroll
    for (int i = 0; i < 3; ++i) {
        float d = vals[i] - mu;
        vs += d * d;
    }
#pragma unroll
    for (int off = 32; off > 0; off >>= 1) vs += __shfl_down(vs, off, 64);
    if ((t & 63) == 0) red[4 + (t >> 6)] = vs;
    __syncthreads();
    const float var = (red[4] + red[5] + red[6] + red[7]) * (1.0f / DMODEL);
    const float inv = rsqrtf(var + 1e-12f);

#pragma unroll
    for (int i = 0; i < 3; ++i) {
        int c = t + i * 256;
        float v = (vals[i] - mu) * inv * gw[c] + bw[c];
        out[(size_t)row * DMODEL + c] = v;
        ((bf16_t*)outb)[(size_t)row * DMODEL + c] = (bf16_t)v;
    }
}

// ---------------------------------------------------------------------------
// out = LayerNorm(p0 + p1 + p2 + p3 + res); fp32 out + bf16 shadow.  (LN2,
// FF2 split-K=4).  Note p3 may alias out (hbuf): each block reads row r of
// p3 before writing row r of out; blocks touch disjoint rows -> safe.
// ---------------------------------------------------------------------------
__global__ __launch_bounds__(256) void add_ln5_kernel(
    const float* __restrict__ p0, const float* __restrict__ p1,
    const float* __restrict__ p2, const float* __restrict__ p3,
    const float* __restrict__ res,
    const float* __restrict__ gw, const float* __restrict__ bw,
    float* __restrict__ out, ushort* __restrict__ outb)
{
    const int row = blockIdx.x;
    const int t = threadIdx.x;
    __shared__ float red[8];

    const float* a0 = p0 + (size_t)row * DMODEL;
    const float* a1 = p1 + (size_t)row * DMODEL;
    const float* a2 = p2 + (size_t)row * DMODEL;
    const float* a3 = p3 + (size_t)row * DMODEL;
    const float* rr = res + (size_t)row * DMODEL;

    float vals[3];
    float s = 0.f;
#pragma unroll
    for (int i = 0; i < 3; ++i) {
        int c = t + i * 256;
        vals[i] = (a0[c] + a1[c]) + (a2[c] + a3[c]) + rr[c];
        s += vals[i];
    }
#pragma unroll
    for (int off = 32; off > 0; off >>= 1) s += __shfl_down(s, off, 64);
    if ((t & 63) == 0) red[t >> 6] = s;
    __syncthreads();
    const float mu = (red[0] + red[1] + red[2] + red[3]) * (1.0f / DMODEL);

    float vs = 0.f;
#pragma unroll
    for (int i = 0; i < 3; ++i) {
        float d = vals[i] - mu;
        vs += d * d;
    }
#pragma unroll
    for (int off = 32; off > 0; off >>= 1) vs += __shfl_down(vs, off, 64);
    if ((t & 63) == 0) red[4 + (t >> 6)] = vs;
    __syncthreads();
    const float var = (red[4] + red[5] + red[6] + red[7]) * (1.0f / DMODEL);
    const float inv = rsqrtf(var + 1e-12f);

#pragma unroll
    for (int i = 0; i < 3; ++i) {
        int c = t + i * 256;
        float v = (vals[i] - mu) * inv * gw[c] + bw[c];
        out[(size_t)row * DMODEL + c] = v;
        ((bf16_t*)outb)[(size_t)row * DMODEL + c] = (bf16_t)v;
    }
}

// ---------------------------------------------------------------------------
extern "C" void kernel_launch(void* const* d_in, const int* in_sizes, int n_in,
                              void* d_out, int out_size, void* d_ws, size_t ws_size,
                              hipStream_t stream)
{
    const float* x    = (const float*)d_in[0];
    const int*   mask = (const int*)d_in[1];
    const float* Wq = (const float*)d_in[2];
    const float* bq = (const float*)d_in[3];
    const float* Wk = (const float*)d_in[4];
    const float* bk = (const float*)d_in[5];
    const float* Wv = (const float*)d_in[6];
    const float* bv = (const float*)d_in[7];
    const float* Wo = (const float*)d_in[8];
    const float* bo = (const float*)d_in[9];
    const float* ln1g = (const float*)d_in[10];
    const float* ln1b = (const float*)d_in[11];
    const float* W1 = (const float*)d_in[12];
    const float* b1 = (const float*)d_in[13];
    const float* W2 = (const float*)d_in[14];
    const float* b2 = (const float*)d_in[15];
    const float* ln2g = (const float*)d_in[16];
    const float* ln2b = (const float*)d_in[17];

    // ---- workspace layout (~102 MB) ----
    float* f32b = (float*)d_ws;
    float* hbuf = f32b;            // h residual (fp32); also FF2 partial 3
    float* f1   = f32b + ND;       // split-K partial 0
    float* h2   = f32b + 2 * ND;   // h2 residual (fp32)
    ushort* ub  = (ushort*)(f32b + 3 * ND);
    ushort* qb  = ub;                          // q bf16 (scaled)
    ushort* kb  = ub + ND;                     // k bf16
    ushort* vtb = ub + 2 * ND;                 // v^T bf16 [b,h,d,s]
    ushort* hff = ub + 3 * ND;                 // h2 bf16 shadow (FF1 input)
    ushort* U   = ub + 4 * ND;                 // gelu-out bf16 (NTOK x FF)
    ushort* ctxb = U;                          // ctx bf16 (aliases U head)
    ushort* hqkv = U;                          // h bf16 shadow (qkv input;
                                               // aliases U head, disjoint life)
    ushort* Wqkvt = U + (size_t)NTOK * FFDIM;  // 2304 x 768 contiguous
    ushort* Wot = Wqkvt + 3 * 768 * 768;
    ushort* W1t = Wot + 768 * 768;             // 3072 x 768
    ushort* W2t = W1t + (size_t)768 * 3072;    // 768 x 3072

    // split-K partials for FF2 (dead-buffer overlays, all fp32 ND):
    //   p1 = qb+kb (dead: attn consumed q,k)
    //   p2 = vtb+hff (dead: attn consumed v; FF1 consumed hff)
    //   p3 = hbuf (dead: LN1 consumed residual h; LN2 reads row then
    //        rewrites same row as new h)
    float* p1 = (float*)ub;
    float* p2 = (float*)(ub + 2 * ND);
    float* p3 = hbuf;

    hipMemcpyAsync(hbuf, x, ND * sizeof(float), hipMemcpyDeviceToDevice, stream);
    f2bf_kernel<<<(int)(ND / 1024), 256, 0, stream>>>(x, hqkv);

    const dim3 gQKV(18, 64);        // N=2304, 64x128, 1152 wgs
    const dim3 gSKo(6, 64, 2);      // attn-out: N=768, split-K=2, 768 wgs
    const dim3 gSK4(6, 64, 4);      // FF2: N=768, split-K=4, 1536 wgs
    const dim3 gFF(24, 64);         // FF1: N=3072, 64x128, 1536 wgs
    const dim3 gA(SEQ / 64, NHEAD, BATCH);

    for (int l = 0; l < NLAYER; ++l) {
        const float* Wq_l = Wq + (size_t)l * DMODEL * DMODEL;
        const float* Wk_l = Wk + (size_t)l * DMODEL * DMODEL;
        const float* Wv_l = Wv + (size_t)l * DMODEL * DMODEL;
        const float* Wo_l = Wo + (size_t)l * DMODEL * DMODEL;
        const float* W1_l = W1 + (size_t)l * DMODEL * FFDIM;
        const float* W2_l = W2 + (size_t)l * FFDIM * DMODEL;

        transpose_w<<<6912, 256, 0, stream>>>(Wq_l, Wk_l, Wv_l, Wo_l, W1_l, W2_l,
                                              Wqkvt, Wqkvt + 768 * 768,
                                              Wqkvt + 2 * 768 * 768, Wot, W1t, W2t);

        gemm_qkv<<<gQKV, 256, 0, stream>>>(hqkv, Wqkvt,
                                           bq + (size_t)l * DMODEL,
                                           bk + (size_t)l * DMODEL,
                                           bv + (size_t)l * DMODEL,
                                           qb, kb, vtb);

        attn_mfma<<<gA, 256, 0, stream>>>(qb, kb, vtb, mask, ctxb);

        // sa = ctx @ Wo + bo, split-K=2 -> partials f1 (z=0), p1 (z=1)
        gemm_mfma_sk<<<gSKo, 256, 0, stream>>>(ctxb, Wot, bo + (size_t)l * DMODEL,
                                               f1, p1, p1, p1,
                                               NTOK, DMODEL, DMODEL, DMODEL / 2);

        // h2 = LN(f1 + p1 + h)
        add_ln3_kernel<<<NTOK, 256, 0, stream>>>(f1, p1, hbuf,
                                                 ln1g + (size_t)l * DMODEL,
                                                 ln1b + (size_t)l * DMODEL, h2, hff);

        gemm_mfma<<<gFF, 256, 0, stream>>>(hff, W1t, b1 + (size_t)l * FFDIM,
                                           nullptr, U, NTOK, DMODEL, FFDIM, 1);

        // ffn_out = U @ W2 + b2, split-K=4 -> f1, p1, p2, p3
        gemm_mfma_sk<<<gSK4, 256, 0, stream>>>(U, W2t, b2 + (size_t)l * DMODEL,
                                               f1, p1, p2, p3,
                                               NTOK, FFDIM, DMODEL, FFDIM / 4);

        // h = LN(f1 + p1 + p2 + p3 + h2); last layer -> d_out
        float* hout = (l == NLAYER - 1) ? (float*)d_out : hbuf;
        add_ln5_kernel<<<NTOK, 256, 0, stream>>>(f1, p1, p2, p3, h2,
                                                 ln2g + (size_t)l * DMODEL,
                                                 ln2b + (size_t)l * DMODEL, hout, hqkv);
    }
}

// Round 6
// 1247.166 us; speedup vs baseline: 1.0705x; 1.0705x over previous
//
#include <hip/hip_runtime.h>
#include <math.h>

#define NLAYER 6
#define DMODEL 768
#define NHEAD 12
#define DHEAD 64
#define FFDIM 3072
#define SEQ 512
#define BATCH 8
#define NTOK (BATCH * SEQ) /* 4096 */
#define ND ((size_t)NTOK * DMODEL)

typedef __bf16 bf16_t;
typedef __bf16 bf16x8 __attribute__((ext_vector_type(8)));
typedef float f32x4 __attribute__((ext_vector_type(4)));

__device__ __forceinline__ float bf2f(ushort u) {
    return __uint_as_float(((unsigned int)u) << 16);
}
union BFU { __bf16 h; ushort u; };
__device__ __forceinline__ ushort f2b(float x) { BFU c; c.h = (__bf16)x; return c.u; }

#define GLDS(gp, lp) __builtin_amdgcn_global_load_lds( \
    (const __attribute__((address_space(1))) void*)(gp), \
    (__attribute__((address_space(3))) void*)(lp), 16, 0, 0)

// ---------------------------------------------------------------------------
// bf16 MFMA GEMM (R2 config — best measured): 128x128 tile, BK=32, 2-phase
// dbuf, 4 waves each 64x64 (acc[4][4]). + XCD swizzle (FETCH −20%, R3).
// NOTE (R0-R5 ledger): serial / drain-0 dbuf / counted-vmcnt depth-2 all
// land at ~9.7 ns per wave-MFMA at >=3 blocks/CU; 6 blocks/CU, BK=64, and
// <3/CU are worse. Do not re-litigate without a structurally new schedule.
// act: 0 none, 1 exact gelu.  Writes Cf (fp32) or Cb (bf16). Used for FF1.
// ---------------------------------------------------------------------------
__global__ __launch_bounds__(256) void gemm_mfma(
    const ushort* __restrict__ A, const ushort* __restrict__ Bt,
    const float* __restrict__ bias, float* __restrict__ Cf,
    ushort* __restrict__ Cb, int M, int K, int N, int act)
{
    __shared__ __align__(16) ushort As[8192];   // 2 x (128x32)
    __shared__ __align__(16) ushort Bs[8192];   // 2 x (128x32)

    const int t = threadIdx.x;
    const int w = t >> 6, l = t & 63;
    const int wr = w >> 1, wc = w & 1;

    const int hw = blockIdx.x + gridDim.x * blockIdx.y;
    const int nwg = gridDim.x * gridDim.y;      // divisible by 8
    const int sw = (hw & 7) * (nwg >> 3) + (hw >> 3);
    const int bx = sw % gridDim.x, by = sw / gridDim.x;

    const int row0 = by * 128, col0 = bx * 128;

    f32x4 acc[4][4];
#pragma unroll
    for (int mi = 0; mi < 4; ++mi)
#pragma unroll
        for (int ni = 0; ni < 4; ++ni)
#pragma unroll
            for (int e = 0; e < 4; ++e) acc[mi][ni][e] = 0.f;

    const int c0 = t,       r0 = c0 >> 2, kg0 = (c0 & 3) ^ ((r0 >> 1) & 3);
    const int c1 = t + 256, r1 = c1 >> 2, kg1 = (c1 & 3) ^ ((r1 >> 1) & 3);
    const ushort* gA0 = A + (size_t)(row0 + r0) * K + kg0 * 8;
    const ushort* gA1 = A + (size_t)(row0 + r1) * K + kg1 * 8;
    const ushort* gB0 = Bt + (size_t)(col0 + r0) * K + kg0 * 8;
    const ushort* gB1 = Bt + (size_t)(col0 + r1) * K + kg1 * 8;

    const int lm = l & 15, lq = l >> 4;
    int aoff[4], boff[4];
#pragma unroll
    for (int mi = 0; mi < 4; ++mi) {
        int m = wr * 64 + mi * 16 + lm;
        aoff[mi] = m * 32 + (lq ^ ((m >> 1) & 3)) * 8;
    }
#pragma unroll
    for (int ni = 0; ni < 4; ++ni) {
        int n = wc * 64 + ni * 16 + lm;
        boff[ni] = n * 32 + (lq ^ ((n >> 1) & 3)) * 8;
    }

#define STAGE_FF(b, k0) do {                                  \
        GLDS(gA0 + (k0), &As[(b) * 4096 + w * 512]);          \
        GLDS(gA1 + (k0), &As[(b) * 4096 + 2048 + w * 512]);   \
        GLDS(gB0 + (k0), &Bs[(b) * 4096 + w * 512]);          \
        GLDS(gB1 + (k0), &Bs[(b) * 4096 + 2048 + w * 512]);   \
    } while (0)

#define COMPUTE_FF(b) do {                                                  \
        bf16x8 af[4], bfr[4];                                               \
        _Pragma("unroll")                                                   \
        for (int mi = 0; mi < 4; ++mi)                                      \
            af[mi] = *(const bf16x8*)&As[(b) * 4096 + aoff[mi]];            \
        _Pragma("unroll")                                                   \
        for (int ni = 0; ni < 4; ++ni)                                      \
            bfr[ni] = *(const bf16x8*)&Bs[(b) * 4096 + boff[ni]];           \
        _Pragma("unroll")                                                   \
        for (int mi = 0; mi < 4; ++mi)                                      \
            _Pragma("unroll")                                               \
            for (int ni = 0; ni < 4; ++ni)                                  \
                acc[mi][ni] = __builtin_amdgcn_mfma_f32_16x16x32_bf16(      \
                    af[mi], bfr[ni], acc[mi][ni], 0, 0, 0);                 \
    } while (0)

    const int nst = K >> 5;
    STAGE_FF(0, 0);
    __syncthreads();
    int cur = 0;
    for (int s = 0; s < nst - 1; ++s) {
        STAGE_FF(cur ^ 1, (s + 1) * 32);
        COMPUTE_FF(cur);
        __syncthreads();
        cur ^= 1;
    }
    COMPUTE_FF(cur);

#pragma unroll
    for (int mi = 0; mi < 4; ++mi) {
        int rowb = row0 + wr * 64 + mi * 16 + lq * 4;
#pragma unroll
        for (int ni = 0; ni < 4; ++ni) {
            int col = col0 + wc * 64 + ni * 16 + lm;
            float bv = bias[col];
#pragma unroll
            for (int r = 0; r < 4; ++r) {
                float v = acc[mi][ni][r] + bv;
                if (act == 1) v = 0.5f * v * (1.0f + erff(v * 0.70710678118654752f));
                size_t idx = (size_t)(rowb + r) * N + col;
                if (Cb) ((bf16_t*)Cb)[idx] = (bf16_t)v;
                else    Cf[idx] = v;
            }
        }
    }
#undef STAGE_FF
#undef COMPUTE_FF
}

// ---------------------------------------------------------------------------
// Split-K bf16 MFMA GEMM (R2 config): 64x128 tile, BK=32, 2-phase dbuf,
// split-K=2 + XCD swizzle (hardcoded for grid (6,64,2)).
// 4 waves 2x2, wave = 32x64 via acc[2][4]. Bias folded into split 0.
// ---------------------------------------------------------------------------
__global__ __launch_bounds__(256) void gemm_mfma_sk(
    const ushort* __restrict__ A, const ushort* __restrict__ Bt,
    const float* __restrict__ bias, float* __restrict__ P0,
    float* __restrict__ P1, int M, int K, int N, int kLen)
{
    __shared__ __align__(16) ushort As[4096];   // 2 x (64x32)
    __shared__ __align__(16) ushort Bs[8192];   // 2 x (128x32)

    const int t = threadIdx.x;
    const int w = t >> 6, l = t & 63;
    const int wr = w >> 1, wc = w & 1;

    // grid (6,64,2) -> 768 wgs; chunked XCD swizzle (96 tiles/XCD)
    const int hw = blockIdx.x + 6 * blockIdx.y + 384 * blockIdx.z;
    const int sw = (hw & 7) * 96 + (hw >> 3);
    const int z  = sw / 384;
    const int rr_ = sw - z * 384;
    const int bx = rr_ % 6, by = rr_ / 6;

    const int row0 = by * 64, col0 = bx * 128;
    const int kOff = z * kLen;
    float* Pz = (z == 0) ? P0 : P1;

    f32x4 acc[2][4];
#pragma unroll
    for (int mi = 0; mi < 2; ++mi)
#pragma unroll
        for (int ni = 0; ni < 4; ++ni)
#pragma unroll
            for (int e = 0; e < 4; ++e) acc[mi][ni][e] = 0.f;

    const int rS = t >> 2, kg = (t & 3) ^ ((rS >> 1) & 3);
    const ushort* gA  = A  + (size_t)(row0 + rS) * K + kg * 8;
    const ushort* gB0 = Bt + (size_t)(col0 + rS) * K + kg * 8;
    const ushort* gB1 = Bt + (size_t)(col0 + 64 + rS) * K + kg * 8;

    const int lm = l & 15, lq = l >> 4;
    int aoff[2], boff[4];
#pragma unroll
    for (int mi = 0; mi < 2; ++mi) {
        int m = wr * 32 + mi * 16 + lm;
        aoff[mi] = m * 32 + (lq ^ ((m >> 1) & 3)) * 8;
    }
#pragma unroll
    for (int ni = 0; ni < 4; ++ni) {
        int n = wc * 64 + ni * 16 + lm;
        boff[ni] = n * 32 + (lq ^ ((n >> 1) & 3)) * 8;
    }

#define STAGE_SK(b, k0) do {                                  \
        GLDS(gA  + (k0), &As[(b) * 2048 + w * 512]);          \
        GLDS(gB0 + (k0), &Bs[(b) * 4096 + w * 512]);          \
        GLDS(gB1 + (k0), &Bs[(b) * 4096 + 2048 + w * 512]);   \
    } while (0)

#define COMPUTE_SK(b) do {                                                  \
        bf16x8 af[2], bfr[4];                                               \
        _Pragma("unroll")                                                   \
        for (int mi = 0; mi < 2; ++mi)                                      \
            af[mi] = *(const bf16x8*)&As[(b) * 2048 + aoff[mi]];            \
        _Pragma("unroll")                                                   \
        for (int ni = 0; ni < 4; ++ni)                                      \
            bfr[ni] = *(const bf16x8*)&Bs[(b) * 4096 + boff[ni]];           \
        _Pragma("unroll")                                                   \
        for (int mi = 0; mi < 2; ++mi)                                      \
            _Pragma("unroll")                                               \
            for (int ni = 0; ni < 4; ++ni)                                  \
                acc[mi][ni] = __builtin_amdgcn_mfma_f32_16x16x32_bf16(      \
                    af[mi], bfr[ni], acc[mi][ni], 0, 0, 0);                 \
    } while (0)

    const int nst = kLen >> 5;
    STAGE_SK(0, kOff);
    __syncthreads();
    int cur = 0;
    for (int s = 0; s < nst - 1; ++s) {
        STAGE_SK(cur ^ 1, kOff + (s + 1) * 32);
        COMPUTE_SK(cur);
        __syncthreads();
        cur ^= 1;
    }
    COMPUTE_SK(cur);

#pragma unroll
    for (int mi = 0; mi < 2; ++mi) {
        int rowb = row0 + wr * 32 + mi * 16 + lq * 4;
#pragma unroll
        for (int ni = 0; ni < 4; ++ni) {
            int col = col0 + wc * 64 + ni * 16 + lm;
            float bv = (z == 0) ? bias[col] : 0.f;
#pragma unroll
            for (int r = 0; r < 4; ++r)
                Pz[(size_t)(rowb + r) * N + col] = acc[mi][ni][r] + bv;
        }
    }
#undef STAGE_SK
#undef COMPUTE_SK
}

// ---------------------------------------------------------------------------
// Fused QKV GEMM (R2 config): 64x128 tile, BK=32, 2-phase dbuf + XCD swizzle
// (hardcoded for grid (18,64)). A (M x 768) @ Wqkvt^T (2304 x 768) ->
// q (scaled, token-major bf16), k (token-major bf16),
// v (TRANSPOSED [b,h,d,s] bf16 for attn PV).
// ---------------------------------------------------------------------------
__global__ __launch_bounds__(256) void gemm_qkv(
    const ushort* __restrict__ A, const ushort* __restrict__ Bt,
    const float* __restrict__ bq, const float* __restrict__ bk,
    const float* __restrict__ bv,
    ushort* __restrict__ qb, ushort* __restrict__ kb, ushort* __restrict__ vtb)
{
    __shared__ __align__(16) ushort As[4096];   // 2 x (64x32)
    __shared__ __align__(16) ushort Bs[8192];   // 2 x (128x32)

    const int K = DMODEL;
    const int t = threadIdx.x;
    const int w = t >> 6, l = t & 63;
    const int wr = w >> 1, wc = w & 1;

    const int hw = blockIdx.x + 18 * blockIdx.y;    // grid (18,64) = 1152
    const int sw = (hw & 7) * 144 + (hw >> 3);
    const int bx = sw % 18, by = sw / 18;

    const int row0 = by * 64, col0 = bx * 128;
    const int seg = bx / 6;            // 0=q 1=k 2=v

    f32x4 acc[2][4];
#pragma unroll
    for (int mi = 0; mi < 2; ++mi)
#pragma unroll
        for (int ni = 0; ni < 4; ++ni)
#pragma unroll
            for (int e = 0; e < 4; ++e) acc[mi][ni][e] = 0.f;

    const int rS = t >> 2, kg = (t & 3) ^ ((rS >> 1) & 3);
    const ushort* gA  = A  + (size_t)(row0 + rS) * K + kg * 8;
    const ushort* gB0 = Bt + (size_t)(col0 + rS) * K + kg * 8;
    const ushort* gB1 = Bt + (size_t)(col0 + 64 + rS) * K + kg * 8;

    const int lm = l & 15, lq = l >> 4;
    int aoff[2], boff[4];
#pragma unroll
    for (int mi = 0; mi < 2; ++mi) {
        int m = wr * 32 + mi * 16 + lm;
        aoff[mi] = m * 32 + (lq ^ ((m >> 1) & 3)) * 8;
    }
#pragma unroll
    for (int ni = 0; ni < 4; ++ni) {
        int n = wc * 64 + ni * 16 + lm;
        boff[ni] = n * 32 + (lq ^ ((n >> 1) & 3)) * 8;
    }

#define STAGE_QKV(b, k0) do {                                 \
        GLDS(gA  + (k0), &As[(b) * 2048 + w * 512]);          \
        GLDS(gB0 + (k0), &Bs[(b) * 4096 + w * 512]);          \
        GLDS(gB1 + (k0), &Bs[(b) * 4096 + 2048 + w * 512]);   \
    } while (0)

#define COMPUTE_QKV(b) do {                                                 \
        bf16x8 af[2], bfr[4];                                               \
        _Pragma("unroll")                                                   \
        for (int mi = 0; mi < 2; ++mi)                                      \
            af[mi] = *(const bf16x8*)&As[(b) * 2048 + aoff[mi]];            \
        _Pragma("unroll")                                                   \
        for (int ni = 0; ni < 4; ++ni)                                      \
            bfr[ni] = *(const bf16x8*)&Bs[(b) * 4096 + boff[ni]];           \
        _Pragma("unroll")                                                   \
        for (int mi = 0; mi < 2; ++mi)                                      \
            _Pragma("unroll")                                               \
            for (int ni = 0; ni < 4; ++ni)                                  \
                acc[mi][ni] = __builtin_amdgcn_mfma_f32_16x16x32_bf16(      \
                    af[mi], bfr[ni], acc[mi][ni], 0, 0, 0);                 \
    } while (0)

    const int nst = K >> 5;   // 24
    STAGE_QKV(0, 0);
    __syncthreads();
    int cur = 0;
    for (int s = 0; s < nst - 1; ++s) {
        STAGE_QKV(cur ^ 1, (s + 1) * 32);
        COMPUTE_QKV(cur);
        __syncthreads();
        cur ^= 1;
    }
    COMPUTE_QKV(cur);

    const float* bp = (seg == 0) ? bq : (seg == 1) ? bk : bv;
    const float sc = (seg == 0) ? 0.125f : 1.0f;
#pragma unroll
    for (int mi = 0; mi < 2; ++mi) {
        int rowb = row0 + wr * 32 + mi * 16 + lq * 4;
#pragma unroll
        for (int ni = 0; ni < 4; ++ni) {
            int col = col0 + wc * 64 + ni * 16 + lm;
            int lcol = col - seg * 768;
            float bvv = bp[lcol];
            if (seg == 2) {
                int hh = lcol >> 6, dd = lcol & 63;
                int bb = rowb >> 9, ss = rowb & 511;
                ushort4 o;
                o.x = f2b(acc[mi][ni][0] + bvv);
                o.y = f2b(acc[mi][ni][1] + bvv);
                o.z = f2b(acc[mi][ni][2] + bvv);
                o.w = f2b(acc[mi][ni][3] + bvv);
                *(ushort4*)&vtb[(((size_t)(bb * NHEAD + hh)) * DHEAD + dd) * SEQ + ss] = o;
            } else {
                ushort* dst = seg ? kb : qb;
#pragma unroll
                for (int r = 0; r < 4; ++r)
                    dst[(size_t)(rowb + r) * DMODEL + lcol] = f2b((acc[mi][ni][r] + bvv) * sc);
            }
        }
    }
#undef STAGE_QKV
#undef COMPUTE_QKV
}

// ---------------------------------------------------------------------------
// MFMA flash attention (unchanged).
// ---------------------------------------------------------------------------
#define QSTR 72

__global__ __launch_bounds__(256) void attn_mfma(
    const ushort* __restrict__ qb, const ushort* __restrict__ kb,
    const ushort* __restrict__ vtb, const int* __restrict__ mask,
    ushort* __restrict__ ctxb)
{
    __shared__ __align__(16) ushort Qs[64 * QSTR];
    __shared__ __align__(16) ushort Ks[64 * QSTR];
    __shared__ __align__(16) ushort Vs[64 * QSTR];
    __shared__ __align__(16) ushort Ps[64 * QSTR];
    __shared__ float Ma[64];

    const int qt = blockIdx.x, h = blockIdx.y, b = blockIdx.z;
    const int t = threadIdx.x;
    const int w = t >> 6, l = t & 63;
    const int lm = l & 15, lq = l >> 4;

#pragma unroll
    for (int i = 0; i < 2; ++i) {
        int ch = t + i * 256;
        int r = ch >> 3, c8 = ch & 7;
        *(uint4*)&Qs[r * QSTR + c8 * 8] =
            *(const uint4*)&qb[((size_t)(b * SEQ + qt * 64 + r)) * DMODEL + h * DHEAD + c8 * 8];
    }

    f32x4 O[4];
#pragma unroll
    for (int n0 = 0; n0 < 4; ++n0)
#pragma unroll
        for (int e = 0; e < 4; ++e) O[n0][e] = 0.f;
    float mrow[4] = {-3.4e38f, -3.4e38f, -3.4e38f, -3.4e38f};
    float lrow[4] = {0.f, 0.f, 0.f, 0.f};

    const int qrow = w * 16 + lm;
    const int prow = w * 16 + lq * 4;

    for (int kt = 0; kt < SEQ / 64; ++kt) {
#pragma unroll
        for (int i = 0; i < 2; ++i) {
            int ch = t + i * 256;
            int r = ch >> 3, c8 = ch & 7;
            *(uint4*)&Ks[r * QSTR + c8 * 8] =
                *(const uint4*)&kb[((size_t)(b * SEQ + kt * 64 + r)) * DMODEL + h * DHEAD + c8 * 8];
            *(uint4*)&Vs[r * QSTR + c8 * 8] =
                *(const uint4*)&vtb[(((size_t)(b * NHEAD + h)) * DHEAD + r) * SEQ + kt * 64 + c8 * 8];
        }
        if (t < 64) Ma[t] = (mask[b * SEQ + kt * 64 + t] == 0) ? -1e9f : 0.f;
        __syncthreads();

        bf16x8 aq0 = *(const bf16x8*)&Qs[qrow * QSTR + lq * 8];
        bf16x8 aq1 = *(const bf16x8*)&Qs[qrow * QSTR + lq * 8 + 32];
        f32x4 S[4];
#pragma unroll
        for (int n0 = 0; n0 < 4; ++n0) {
#pragma unroll
            for (int e = 0; e < 4; ++e) S[n0][e] = 0.f;
            bf16x8 b0 = *(const bf16x8*)&Ks[(n0 * 16 + lm) * QSTR + lq * 8];
            bf16x8 b1 = *(const bf16x8*)&Ks[(n0 * 16 + lm) * QSTR + lq * 8 + 32];
            S[n0] = __builtin_amdgcn_mfma_f32_16x16x32_bf16(aq0, b0, S[n0], 0, 0, 0);
            S[n0] = __builtin_amdgcn_mfma_f32_16x16x32_bf16(aq1, b1, S[n0], 0, 0, 0);
        }

        float ma4[4];
#pragma unroll
        for (int n0 = 0; n0 < 4; ++n0) ma4[n0] = Ma[n0 * 16 + lm];
#pragma unroll
        for (int n0 = 0; n0 < 4; ++n0)
#pragma unroll
            for (int r = 0; r < 4; ++r) S[n0][r] += ma4[n0];

        float tm[4];
#pragma unroll
        for (int r = 0; r < 4; ++r)
            tm[r] = fmaxf(fmaxf(S[0][r], S[1][r]), fmaxf(S[2][r], S[3][r]));
#pragma unroll
        for (int off = 1; off < 16; off <<= 1)
#pragma unroll
            for (int r = 0; r < 4; ++r)
                tm[r] = fmaxf(tm[r], __shfl_xor(tm[r], off, 64));

        float al[4], ts[4];
#pragma unroll
        for (int r = 0; r < 4; ++r) {
            float mn = fmaxf(mrow[r], tm[r]);
            al[r] = __expf(mrow[r] - mn);
            mrow[r] = mn;
            ts[r] = 0.f;
        }
#pragma unroll
        for (int n0 = 0; n0 < 4; ++n0)
#pragma unroll
            for (int r = 0; r < 4; ++r) {
                float p = __expf(S[n0][r] - mrow[r]);
                ts[r] += p;
                Ps[(prow + r) * QSTR + n0 * 16 + lm] = f2b(p);
            }
#pragma unroll
        for (int off = 1; off < 16; off <<= 1)
#pragma unroll
            for (int r = 0; r < 4; ++r)
                ts[r] += __shfl_xor(ts[r], off, 64);
#pragma unroll
        for (int r = 0; r < 4; ++r) lrow[r] = lrow[r] * al[r] + ts[r];
#pragma unroll
        for (int n0 = 0; n0 < 4; ++n0)
#pragma unroll
            for (int r = 0; r < 4; ++r) O[n0][r] *= al[r];

        bf16x8 ap0 = *(const bf16x8*)&Ps[qrow * QSTR + lq * 8];
        bf16x8 ap1 = *(const bf16x8*)&Ps[qrow * QSTR + lq * 8 + 32];
#pragma unroll
        for (int n0 = 0; n0 < 4; ++n0) {
            bf16x8 v0 = *(const bf16x8*)&Vs[(n0 * 16 + lm) * QSTR + lq * 8];
            bf16x8 v1 = *(const bf16x8*)&Vs[(n0 * 16 + lm) * QSTR + lq * 8 + 32];
            O[n0] = __builtin_amdgcn_mfma_f32_16x16x32_bf16(ap0, v0, O[n0], 0, 0, 0);
            O[n0] = __builtin_amdgcn_mfma_f32_16x16x32_bf16(ap1, v1, O[n0], 0, 0, 0);
        }
        __syncthreads();
    }

    float inv[4];
#pragma unroll
    for (int r = 0; r < 4; ++r) inv[r] = 1.f / lrow[r];
#pragma unroll
    for (int n0 = 0; n0 < 4; ++n0)
#pragma unroll
        for (int r = 0; r < 4; ++r)
            Ks[(prow + r) * QSTR + n0 * 16 + lm] = f2b(O[n0][r] * inv[r]);
    __syncthreads();
#pragma unroll
    for (int i = 0; i < 2; ++i) {
        int ch = t + i * 256;
        int r = ch >> 3, c8 = ch & 7;
        *(uint4*)&ctxb[((size_t)(b * SEQ + qt * 64 + r)) * DMODEL + h * DHEAD + c8 * 8] =
            *(const uint4*)&Ks[r * QSTR + c8 * 8];
    }
}

// ---------------------------------------------------------------------------
// Per-layer weight transpose+convert: K x N fp32 -> N x K bf16.
// Write path vectorized to ushort2 (was scalar 2B stores).
// ---------------------------------------------------------------------------
__global__ __launch_bounds__(256) void transpose_w(
    const float* __restrict__ Wq, const float* __restrict__ Wk,
    const float* __restrict__ Wv, const float* __restrict__ Wo,
    const float* __restrict__ W1, const float* __restrict__ W2,
    ushort* __restrict__ Wqt, ushort* __restrict__ Wkt,
    ushort* __restrict__ Wvt, ushort* __restrict__ Wot,
    ushort* __restrict__ W1t, ushort* __restrict__ W2t)
{
    __shared__ float tile[32][33];   // tile[n_local][k_local]
    const int bid = blockIdx.x;
    const float* src; ushort* dst; int K, N, tx, ty;
    if (bid < 2304) {
        int m = bid / 576, tl = bid % 576;
        src = (m == 0) ? Wq : (m == 1) ? Wk : (m == 2) ? Wv : Wo;
        dst = (m == 0) ? Wqt : (m == 1) ? Wkt : (m == 2) ? Wvt : Wot;
        K = 768; N = 768; tx = tl % 24; ty = tl / 24;
    } else if (bid < 4608) {
        int tl = bid - 2304;
        src = W1; dst = W1t; K = 768; N = 3072; tx = tl % 96; ty = tl / 96;
    } else {
        int tl = bid - 4608;
        src = W2; dst = W2t; K = 3072; N = 768; tx = tl % 24; ty = tl / 24;
    }
    const int t = threadIdx.x;
    const int lx = t & 31, ly = t >> 5;
    const int n0 = tx * 32, k0 = ty * 32;
#pragma unroll
    for (int i = 0; i < 4; ++i)
        tile[lx][ly + i * 8] = src[(size_t)(k0 + ly + i * 8) * N + n0 + lx];
    __syncthreads();
    const int kk2 = (t & 15) * 2, nn = t >> 4;   // 2 k's, 16 n-slots
#pragma unroll
    for (int i = 0; i < 2; ++i) {
        int nl = nn + i * 16;
        ushort2 o;
        o.x = f2b(tile[nl][kk2]);
        o.y = f2b(tile[nl][kk2 + 1]);
        *(ushort2*)&dst[(size_t)(n0 + nl) * K + k0 + kk2] = o;
    }
}

// ---------------------------------------------------------------------------
// init: hbuf = x (fp32 copy), hb = bf16(x).  Replaces memcpy + f2bf.
// ---------------------------------------------------------------------------
__global__ __launch_bounds__(256) void init_kernel(
    const float* __restrict__ x, float* __restrict__ hbuf,
    ushort* __restrict__ hb)
{
    const size_t i = ((size_t)blockIdx.x * 256 + threadIdx.x) * 4;
    float4 v = *(const float4*)(x + i);
    *(float4*)(hbuf + i) = v;
    ushort4 o;
    o.x = f2b(v.x); o.y = f2b(v.y); o.z = f2b(v.z); o.w = f2b(v.w);
    *(ushort4*)(hb + i) = o;
}

// ---------------------------------------------------------------------------
// out = LayerNorm(p0 + p1 + res); fp32 out + bf16 shadow.
// float4-vectorized (G13): 192 threads, one float4 per array per thread.
// ---------------------------------------------------------------------------
__global__ __launch_bounds__(192) void add_ln3_kernel(
    const float* __restrict__ p0, const float* __restrict__ p1,
    const float* __restrict__ res,
    const float* __restrict__ gw, const float* __restrict__ bw,
    float* __restrict__ out, ushort* __restrict__ outb)
{
    const int row = blockIdx.x;
    const int t = threadIdx.x;           // 0..191 (192*4 = 768)
    __shared__ float red[6];

    const float4 v0 = ((const float4*)(p0 + (size_t)row * DMODEL))[t];
    const float4 v1 = ((const float4*)(p1 + (size_t)row * DMODEL))[t];
    const float4 v2 = ((const float4*)(res + (size_t)row * DMODEL))[t];

    float4 vv;
    vv.x = v0.x + v1.x + v2.x;
    vv.y = v0.y + v1.y + v2.y;
    vv.z = v0.z + v1.z + v2.z;
    vv.w = v0.w + v1.w + v2.w;

    float s = (vv.x + vv.y) + (vv.z + vv.w);
#pragma unroll
    for (int off = 32; off > 0; off >>= 1) s += __shfl_down(s, off, 64);
    if ((t & 63) == 0) red[t >> 6] = s;
    __syncthreads();
    const float mu = (red[0] + red[1] + red[2]) * (1.0f / DMODEL);

    float dx = vv.x - mu, dy = vv.y - mu, dz = vv.z - mu, dw = vv.w - mu;
    float vs = (dx * dx + dy * dy) + (dz * dz + dw * dw);
#pragma unroll
    for (int off = 32; off > 0; off >>= 1) vs += __shfl_down(vs, off, 64);
    if ((t & 63) == 0) red[3 + (t >> 6)] = vs;
    __syncthreads();
    const float var = (red[3] + red[4] + red[5]) * (1.0f / DMODEL);
    const float inv = rsqrtf(var + 1e-12f);

    const float4 g = ((const float4*)gw)[t];
    const float4 bb = ((const float4*)bw)[t];
    float4 o;
    o.x = dx * inv * g.x + bb.x;
    o.y = dy * inv * g.y + bb.y;
    o.z = dz * inv * g.z + bb.z;
    o.w = dw * inv * g.w + bb.w;
    ((float4*)(out + (size_t)row * DMODEL))[t] = o;
    ushort4 ob;
    ob.x = f2b(o.x); ob.y = f2b(o.y); ob.z = f2b(o.z); ob.w = f2b(o.w);
    ((ushort4*)(outb + (size_t)row * DMODEL * 0 + (size_t)row * DMODEL))[t] = ob;
}

// ---------------------------------------------------------------------------
extern "C" void kernel_launch(void* const* d_in, const int* in_sizes, int n_in,
                              void* d_out, int out_size, void* d_ws, size_t ws_size,
                              hipStream_t stream)
{
    const float* x    = (const float*)d_in[0];
    const int*   mask = (const int*)d_in[1];
    const float* Wq = (const float*)d_in[2];
    const float* bq = (const float*)d_in[3];
    const float* Wk = (const float*)d_in[4];
    const float* bk = (const float*)d_in[5];
    const float* Wv = (const float*)d_in[6];
    const float* bv = (const float*)d_in[7];
    const float* Wo = (const float*)d_in[8];
    const float* bo = (const float*)d_in[9];
    const float* ln1g = (const float*)d_in[10];
    const float* ln1b = (const float*)d_in[11];
    const float* W1 = (const float*)d_in[12];
    const float* b1 = (const float*)d_in[13];
    const float* W2 = (const float*)d_in[14];
    const float* b2 = (const float*)d_in[15];
    const float* ln2g = (const float*)d_in[16];
    const float* ln2b = (const float*)d_in[17];

    // ---- workspace layout (~102 MB) ----
    float* f32b = (float*)d_ws;
    float* hbuf = f32b;            // h residual (fp32)
    float* f1   = f32b + ND;       // split-K partial 0
    float* h2   = f32b + 2 * ND;   // h2 residual (fp32)
    ushort* ub  = (ushort*)(f32b + 3 * ND);
    ushort* qb  = ub;                          // q bf16 (scaled)
    ushort* kb  = ub + ND;                     // k bf16
    ushort* vtb = ub + 2 * ND;                 // v^T bf16 [b,h,d,s]
    ushort* hb  = ub + 3 * ND;                 // h bf16
    ushort* U   = ub + 4 * ND;                 // gelu-out bf16 (NTOK x FF)
    ushort* ctxb = U;                          // ctx bf16 (aliases U; disjoint lifetime)
    ushort* Wqkvt = U + (size_t)NTOK * FFDIM;  // 2304 x 768 contiguous
    ushort* Wot = Wqkvt + 3 * 768 * 768;
    ushort* W1t = Wot + 768 * 768;             // 3072 x 768
    ushort* W2t = W1t + (size_t)768 * 3072;    // 768 x 3072

    // split-K partial 1: ND floats overlaying qb+kb (dead when sk-GEMMs run;
    // rewritten by the NEXT layer's gemm_qkv only after add_ln3 consumed p1)
    float* p1 = (float*)ub;

    init_kernel<<<(int)(ND / 1024), 256, 0, stream>>>(x, hbuf, hb);

    const dim3 gQKV(18, 64);        // N=2304, BM=64
    const dim3 gSK(6, 64, 2);       // N=768, BM=64, split-K=2
    const dim3 gFF(24, 32);         // N=3072, 128x128
    const dim3 gA(SEQ / 64, NHEAD, BATCH);

    for (int l = 0; l < NLAYER; ++l) {
        const float* Wq_l = Wq + (size_t)l * DMODEL * DMODEL;
        const float* Wk_l = Wk + (size_t)l * DMODEL * DMODEL;
        const float* Wv_l = Wv + (size_t)l * DMODEL * DMODEL;
        const float* Wo_l = Wo + (size_t)l * DMODEL * DMODEL;
        const float* W1_l = W1 + (size_t)l * DMODEL * FFDIM;
        const float* W2_l = W2 + (size_t)l * FFDIM * DMODEL;

        transpose_w<<<6912, 256, 0, stream>>>(Wq_l, Wk_l, Wv_l, Wo_l, W1_l, W2_l,
                                              Wqkvt, Wqkvt + 768 * 768,
                                              Wqkvt + 2 * 768 * 768, Wot, W1t, W2t);

        gemm_qkv<<<gQKV, 256, 0, stream>>>(hb, Wqkvt,
                                           bq + (size_t)l * DMODEL,
                                           bk + (size_t)l * DMODEL,
                                           bv + (size_t)l * DMODEL,
                                           qb, kb, vtb);

        attn_mfma<<<gA, 256, 0, stream>>>(qb, kb, vtb, mask, ctxb);

        // sa = ctx @ Wo + bo, split-K=2 -> partials f1 (z=0) and p1 (z=1)
        gemm_mfma_sk<<<gSK, 256, 0, stream>>>(ctxb, Wot, bo + (size_t)l * DMODEL,
                                              f1, p1, NTOK, DMODEL, DMODEL, DMODEL / 2);

        // h2 = LN(f1 + p1 + h)
        add_ln3_kernel<<<NTOK, 192, 0, stream>>>(f1, p1, hbuf,
                                                 ln1g + (size_t)l * DMODEL,
                                                 ln1b + (size_t)l * DMODEL, h2, hb);

        gemm_mfma<<<gFF, 256, 0, stream>>>(hb, W1t, b1 + (size_t)l * FFDIM,
                                           nullptr, U, NTOK, DMODEL, FFDIM, 1);

        // ffn_out = U @ W2 + b2, split-K=2
        gemm_mfma_sk<<<gSK, 256, 0, stream>>>(U, W2t, b2 + (size_t)l * DMODEL,
                                              f1, p1, NTOK, FFDIM, DMODEL, FFDIM / 2);

        // h = LN(f1 + p1 + h2); last layer -> d_out
        float* hout = (l == NLAYER - 1) ? (float*)d_out : hbuf;
        add_ln3_kernel<<<NTOK, 192, 0, stream>>>(f1, p1, h2,
                                                 ln2g + (size_t)l * DMODEL,
                                                 ln2b + (size_t)l * DMODEL, hout, hb);
    }
}

// Round 7
// 1197.104 us; speedup vs baseline: 1.1153x; 1.0418x over previous
//
#include <hip/hip_runtime.h>
#include <math.h>

#define NLAYER 6
#define DMODEL 768
#define NHEAD 12
#define DHEAD 64
#define FFDIM 3072
#define SEQ 512
#define BATCH 8
#define NTOK (BATCH * SEQ) /* 4096 */
#define ND ((size_t)NTOK * DMODEL)

typedef __bf16 bf16_t;
typedef __bf16 bf16x8 __attribute__((ext_vector_type(8)));
typedef float f32x4 __attribute__((ext_vector_type(4)));

__device__ __forceinline__ float bf2f(ushort u) {
    return __uint_as_float(((unsigned int)u) << 16);
}
union BFU { __bf16 h; ushort u; };
__device__ __forceinline__ ushort f2b(float x) { BFU c; c.h = (__bf16)x; return c.u; }

#define GLDS(gp, lp) __builtin_amdgcn_global_load_lds( \
    (const __attribute__((address_space(1))) void*)(gp), \
    (__attribute__((address_space(3))) void*)(lp), 16, 0, 0)

// ---------------------------------------------------------------------------
// bf16 MFMA GEMM (best measured config): 128x128 tile, BK=32, 2-phase dbuf,
// 4 waves each 64x64 (acc[4][4]) + XCD swizzle.
// LEDGER (R0-R6): per-K-step cost ~fixed (~9.7 ns/wave-MFMA) at >=3
// blocks/CU for BK32; BK=64 here costs a resident block (64KB LDS) -> slower.
// act: 0 none, 1 exact gelu.  Used for FF1 only.
// ---------------------------------------------------------------------------
__global__ __launch_bounds__(256) void gemm_mfma(
    const ushort* __restrict__ A, const ushort* __restrict__ Bt,
    const float* __restrict__ bias, float* __restrict__ Cf,
    ushort* __restrict__ Cb, int M, int K, int N, int act)
{
    __shared__ __align__(16) ushort As[8192];   // 2 x (128x32)
    __shared__ __align__(16) ushort Bs[8192];   // 2 x (128x32)

    const int t = threadIdx.x;
    const int w = t >> 6, l = t & 63;
    const int wr = w >> 1, wc = w & 1;

    const int hw = blockIdx.x + gridDim.x * blockIdx.y;
    const int nwg = gridDim.x * gridDim.y;      // divisible by 8
    const int sw = (hw & 7) * (nwg >> 3) + (hw >> 3);
    const int bx = sw % gridDim.x, by = sw / gridDim.x;

    const int row0 = by * 128, col0 = bx * 128;

    f32x4 acc[4][4];
#pragma unroll
    for (int mi = 0; mi < 4; ++mi)
#pragma unroll
        for (int ni = 0; ni < 4; ++ni)
#pragma unroll
            for (int e = 0; e < 4; ++e) acc[mi][ni][e] = 0.f;

    const int c0 = t,       r0 = c0 >> 2, kg0 = (c0 & 3) ^ ((r0 >> 1) & 3);
    const int c1 = t + 256, r1 = c1 >> 2, kg1 = (c1 & 3) ^ ((r1 >> 1) & 3);
    const ushort* gA0 = A + (size_t)(row0 + r0) * K + kg0 * 8;
    const ushort* gA1 = A + (size_t)(row0 + r1) * K + kg1 * 8;
    const ushort* gB0 = Bt + (size_t)(col0 + r0) * K + kg0 * 8;
    const ushort* gB1 = Bt + (size_t)(col0 + r1) * K + kg1 * 8;

    const int lm = l & 15, lq = l >> 4;
    int aoff[4], boff[4];
#pragma unroll
    for (int mi = 0; mi < 4; ++mi) {
        int m = wr * 64 + mi * 16 + lm;
        aoff[mi] = m * 32 + (lq ^ ((m >> 1) & 3)) * 8;
    }
#pragma unroll
    for (int ni = 0; ni < 4; ++ni) {
        int n = wc * 64 + ni * 16 + lm;
        boff[ni] = n * 32 + (lq ^ ((n >> 1) & 3)) * 8;
    }

#define STAGE_FF(b, k0) do {                                  \
        GLDS(gA0 + (k0), &As[(b) * 4096 + w * 512]);          \
        GLDS(gA1 + (k0), &As[(b) * 4096 + 2048 + w * 512]);   \
        GLDS(gB0 + (k0), &Bs[(b) * 4096 + w * 512]);          \
        GLDS(gB1 + (k0), &Bs[(b) * 4096 + 2048 + w * 512]);   \
    } while (0)

#define COMPUTE_FF(b) do {                                                  \
        bf16x8 af[4], bfr[4];                                               \
        _Pragma("unroll")                                                   \
        for (int mi = 0; mi < 4; ++mi)                                      \
            af[mi] = *(const bf16x8*)&As[(b) * 4096 + aoff[mi]];            \
        _Pragma("unroll")                                                   \
        for (int ni = 0; ni < 4; ++ni)                                      \
            bfr[ni] = *(const bf16x8*)&Bs[(b) * 4096 + boff[ni]];           \
        _Pragma("unroll")                                                   \
        for (int mi = 0; mi < 4; ++mi)                                      \
            _Pragma("unroll")                                               \
            for (int ni = 0; ni < 4; ++ni)                                  \
                acc[mi][ni] = __builtin_amdgcn_mfma_f32_16x16x32_bf16(      \
                    af[mi], bfr[ni], acc[mi][ni], 0, 0, 0);                 \
    } while (0)

    const int nst = K >> 5;
    STAGE_FF(0, 0);
    __syncthreads();
    int cur = 0;
    for (int s = 0; s < nst - 1; ++s) {
        STAGE_FF(cur ^ 1, (s + 1) * 32);
        COMPUTE_FF(cur);
        __syncthreads();
        cur ^= 1;
    }
    COMPUTE_FF(cur);

#pragma unroll
    for (int mi = 0; mi < 4; ++mi) {
        int rowb = row0 + wr * 64 + mi * 16 + lq * 4;
#pragma unroll
        for (int ni = 0; ni < 4; ++ni) {
            int col = col0 + wc * 64 + ni * 16 + lm;
            float bv = bias[col];
#pragma unroll
            for (int r = 0; r < 4; ++r) {
                float v = acc[mi][ni][r] + bv;
                if (act == 1) v = 0.5f * v * (1.0f + erff(v * 0.70710678118654752f));
                size_t idx = (size_t)(rowb + r) * N + col;
                if (Cb) ((bf16_t*)Cb)[idx] = (bf16_t)v;
                else    Cf[idx] = v;
            }
        }
    }
#undef STAGE_FF
#undef COMPUTE_FF
}

// ---------------------------------------------------------------------------
// Split-K bf16 MFMA GEMM, 64x128 tile, BK=64 (two stacked 32-col halves),
// 2-phase dbuf + XCD swizzle. 48KB LDS keeps 3 blocks/CU while halving the
// step count — R4 ledger: the BK=64 sk/qkv variants improved ~96 µs total
// (masked there by the FF1 128²/BK64 occupancy regression).
// 4 waves 2x2, wave = 32x64 via acc[2][4]. z selects K-range and explicit
// partial dest (P0 / P1). Bias folded into split 0.
// ---------------------------------------------------------------------------
__global__ __launch_bounds__(256) void gemm_mfma_sk(
    const ushort* __restrict__ A, const ushort* __restrict__ Bt,
    const float* __restrict__ bias, float* __restrict__ P0,
    float* __restrict__ P1, int M, int K, int N, int kLen)
{
    __shared__ __align__(16) ushort As[8192];    // [2 buf][2 half][64x32]
    __shared__ __align__(16) ushort Bs[16384];   // [2 buf][2 half][128x32]

    const int t = threadIdx.x;
    const int w = t >> 6, l = t & 63;
    const int wr = w >> 1, wc = w & 1;

    // grid (6,64,2) -> 768 wgs; chunked XCD swizzle (96 tiles/XCD)
    const int hw = blockIdx.x + 6 * blockIdx.y + 384 * blockIdx.z;
    const int sw = (hw & 7) * 96 + (hw >> 3);
    const int z  = sw / 384;
    const int rr_ = sw - z * 384;
    const int bx = rr_ % 6, by = rr_ / 6;

    const int row0 = by * 64, col0 = bx * 128;
    const int kOff = z * kLen;
    float* Pz = (z == 0) ? P0 : P1;

    f32x4 acc[2][4];
#pragma unroll
    for (int mi = 0; mi < 2; ++mi)
#pragma unroll
        for (int ni = 0; ni < 4; ++ni)
#pragma unroll
            for (int e = 0; e < 4; ++e) acc[mi][ni][e] = 0.f;

    const int rS = t >> 2, kg = (t & 3) ^ ((rS >> 1) & 3);
    const ushort* gA  = A  + (size_t)(row0 + rS) * K + kg * 8;
    const ushort* gB0 = Bt + (size_t)(col0 + rS) * K + kg * 8;
    const ushort* gB1 = Bt + (size_t)(col0 + 64 + rS) * K + kg * 8;

    const int lm = l & 15, lq = l >> 4;
    int aoff[2], boff[4];
#pragma unroll
    for (int mi = 0; mi < 2; ++mi) {
        int m = wr * 32 + mi * 16 + lm;
        aoff[mi] = m * 32 + (lq ^ ((m >> 1) & 3)) * 8;
    }
#pragma unroll
    for (int ni = 0; ni < 4; ++ni) {
        int n = wc * 64 + ni * 16 + lm;
        boff[ni] = n * 32 + (lq ^ ((n >> 1) & 3)) * 8;
    }

#define STAGE_SK(b, k0) do {                                              \
        _Pragma("unroll")                                                 \
        for (int h = 0; h < 2; ++h) {                                     \
            GLDS(gA  + (k0) + h * 32, &As[(b) * 4096 + h * 2048 + w * 512]);        \
            GLDS(gB0 + (k0) + h * 32, &Bs[(b) * 8192 + h * 4096 + w * 512]);        \
            GLDS(gB1 + (k0) + h * 32, &Bs[(b) * 8192 + h * 4096 + 2048 + w * 512]); \
        }                                                                 \
    } while (0)

#define COMPUTE_SK(b) do {                                                  \
        _Pragma("unroll")                                                   \
        for (int h = 0; h < 2; ++h) {                                       \
            bf16x8 af[2], bfr[4];                                           \
            _Pragma("unroll")                                               \
            for (int mi = 0; mi < 2; ++mi)                                  \
                af[mi] = *(const bf16x8*)&As[(b) * 4096 + h * 2048 + aoff[mi]]; \
            _Pragma("unroll")                                               \
            for (int ni = 0; ni < 4; ++ni)                                  \
                bfr[ni] = *(const bf16x8*)&Bs[(b) * 8192 + h * 4096 + boff[ni]]; \
            _Pragma("unroll")                                               \
            for (int mi = 0; mi < 2; ++mi)                                  \
                _Pragma("unroll")                                           \
                for (int ni = 0; ni < 4; ++ni)                              \
                    acc[mi][ni] = __builtin_amdgcn_mfma_f32_16x16x32_bf16(  \
                        af[mi], bfr[ni], acc[mi][ni], 0, 0, 0);             \
        }                                                                   \
    } while (0)

    const int nst = kLen >> 6;
    STAGE_SK(0, kOff);
    __syncthreads();
    int cur = 0;
    for (int s = 0; s < nst - 1; ++s) {
        STAGE_SK(cur ^ 1, kOff + (s + 1) * 64);
        COMPUTE_SK(cur);
        __syncthreads();
        cur ^= 1;
    }
    COMPUTE_SK(cur);

#pragma unroll
    for (int mi = 0; mi < 2; ++mi) {
        int rowb = row0 + wr * 32 + mi * 16 + lq * 4;
#pragma unroll
        for (int ni = 0; ni < 4; ++ni) {
            int col = col0 + wc * 64 + ni * 16 + lm;
            float bv = (z == 0) ? bias[col] : 0.f;
#pragma unroll
            for (int r = 0; r < 4; ++r)
                Pz[(size_t)(rowb + r) * N + col] = acc[mi][ni][r] + bv;
        }
    }
#undef STAGE_SK
#undef COMPUTE_SK
}

// ---------------------------------------------------------------------------
// Fused QKV GEMM, 64x128 tile, BK=64, 2-phase dbuf + XCD swizzle (same
// rationale as gemm_mfma_sk).  A (M x 768) @ Wqkvt^T (2304 x 768) ->
// q (scaled, token-major bf16), k (token-major bf16),
// v (TRANSPOSED [b,h,d,s] bf16 for attn PV).
// ---------------------------------------------------------------------------
__global__ __launch_bounds__(256) void gemm_qkv(
    const ushort* __restrict__ A, const ushort* __restrict__ Bt,
    const float* __restrict__ bq, const float* __restrict__ bk,
    const float* __restrict__ bv,
    ushort* __restrict__ qb, ushort* __restrict__ kb, ushort* __restrict__ vtb)
{
    __shared__ __align__(16) ushort As[8192];    // [2 buf][2 half][64x32]
    __shared__ __align__(16) ushort Bs[16384];   // [2 buf][2 half][128x32]

    const int K = DMODEL;
    const int t = threadIdx.x;
    const int w = t >> 6, l = t & 63;
    const int wr = w >> 1, wc = w & 1;

    // grid (18,64) -> 1152 wgs; chunked XCD swizzle (144 tiles/XCD)
    const int hw = blockIdx.x + 18 * blockIdx.y;
    const int sw = (hw & 7) * 144 + (hw >> 3);
    const int bx = sw % 18, by = sw / 18;

    const int row0 = by * 64, col0 = bx * 128;
    const int seg = bx / 6;            // 0=q 1=k 2=v

    f32x4 acc[2][4];
#pragma unroll
    for (int mi = 0; mi < 2; ++mi)
#pragma unroll
        for (int ni = 0; ni < 4; ++ni)
#pragma unroll
            for (int e = 0; e < 4; ++e) acc[mi][ni][e] = 0.f;

    const int rS = t >> 2, kg = (t & 3) ^ ((rS >> 1) & 3);
    const ushort* gA  = A  + (size_t)(row0 + rS) * K + kg * 8;
    const ushort* gB0 = Bt + (size_t)(col0 + rS) * K + kg * 8;
    const ushort* gB1 = Bt + (size_t)(col0 + 64 + rS) * K + kg * 8;

    const int lm = l & 15, lq = l >> 4;
    int aoff[2], boff[4];
#pragma unroll
    for (int mi = 0; mi < 2; ++mi) {
        int m = wr * 32 + mi * 16 + lm;
        aoff[mi] = m * 32 + (lq ^ ((m >> 1) & 3)) * 8;
    }
#pragma unroll
    for (int ni = 0; ni < 4; ++ni) {
        int n = wc * 64 + ni * 16 + lm;
        boff[ni] = n * 32 + (lq ^ ((n >> 1) & 3)) * 8;
    }

#define STAGE_QKV(b, k0) do {                                             \
        _Pragma("unroll")                                                 \
        for (int h = 0; h < 2; ++h) {                                     \
            GLDS(gA  + (k0) + h * 32, &As[(b) * 4096 + h * 2048 + w * 512]);        \
            GLDS(gB0 + (k0) + h * 32, &Bs[(b) * 8192 + h * 4096 + w * 512]);        \
            GLDS(gB1 + (k0) + h * 32, &Bs[(b) * 8192 + h * 4096 + 2048 + w * 512]); \
        }                                                                 \
    } while (0)

#define COMPUTE_QKV(b) do {                                                 \
        _Pragma("unroll")                                                   \
        for (int h = 0; h < 2; ++h) {                                       \
            bf16x8 af[2], bfr[4];                                           \
            _Pragma("unroll")                                               \
            for (int mi = 0; mi < 2; ++mi)                                  \
                af[mi] = *(const bf16x8*)&As[(b) * 4096 + h * 2048 + aoff[mi]]; \
            _Pragma("unroll")                                               \
            for (int ni = 0; ni < 4; ++ni)                                  \
                bfr[ni] = *(const bf16x8*)&Bs[(b) * 8192 + h * 4096 + boff[ni]]; \
            _Pragma("unroll")                                               \
            for (int mi = 0; mi < 2; ++mi)                                  \
                _Pragma("unroll")                                           \
                for (int ni = 0; ni < 4; ++ni)                              \
                    acc[mi][ni] = __builtin_amdgcn_mfma_f32_16x16x32_bf16(  \
                        af[mi], bfr[ni], acc[mi][ni], 0, 0, 0);             \
        }                                                                   \
    } while (0)

    const int nst = K >> 6;   // 12
    STAGE_QKV(0, 0);
    __syncthreads();
    int cur = 0;
    for (int s = 0; s < nst - 1; ++s) {
        STAGE_QKV(cur ^ 1, (s + 1) * 64);
        COMPUTE_QKV(cur);
        __syncthreads();
        cur ^= 1;
    }
    COMPUTE_QKV(cur);

    const float* bp = (seg == 0) ? bq : (seg == 1) ? bk : bv;
    const float sc = (seg == 0) ? 0.125f : 1.0f;
#pragma unroll
    for (int mi = 0; mi < 2; ++mi) {
        int rowb = row0 + wr * 32 + mi * 16 + lq * 4;
#pragma unroll
        for (int ni = 0; ni < 4; ++ni) {
            int col = col0 + wc * 64 + ni * 16 + lm;
            int lcol = col - seg * 768;
            float bvv = bp[lcol];
            if (seg == 2) {
                int hh = lcol >> 6, dd = lcol & 63;
                int bb = rowb >> 9, ss = rowb & 511;
                ushort4 o;
                o.x = f2b(acc[mi][ni][0] + bvv);
                o.y = f2b(acc[mi][ni][1] + bvv);
                o.z = f2b(acc[mi][ni][2] + bvv);
                o.w = f2b(acc[mi][ni][3] + bvv);
                *(ushort4*)&vtb[(((size_t)(bb * NHEAD + hh)) * DHEAD + dd) * SEQ + ss] = o;
            } else {
                ushort* dst = seg ? kb : qb;
#pragma unroll
                for (int r = 0; r < 4; ++r)
                    dst[(size_t)(rowb + r) * DMODEL + lcol] = f2b((acc[mi][ni][r] + bvv) * sc);
            }
        }
    }
#undef STAGE_QKV
#undef COMPUTE_QKV
}

// ---------------------------------------------------------------------------
// MFMA flash attention (unchanged).
// ---------------------------------------------------------------------------
#define QSTR 72

__global__ __launch_bounds__(256) void attn_mfma(
    const ushort* __restrict__ qb, const ushort* __restrict__ kb,
    const ushort* __restrict__ vtb, const int* __restrict__ mask,
    ushort* __restrict__ ctxb)
{
    __shared__ __align__(16) ushort Qs[64 * QSTR];
    __shared__ __align__(16) ushort Ks[64 * QSTR];
    __shared__ __align__(16) ushort Vs[64 * QSTR];
    __shared__ __align__(16) ushort Ps[64 * QSTR];
    __shared__ float Ma[64];

    const int qt = blockIdx.x, h = blockIdx.y, b = blockIdx.z;
    const int t = threadIdx.x;
    const int w = t >> 6, l = t & 63;
    const int lm = l & 15, lq = l >> 4;

#pragma unroll
    for (int i = 0; i < 2; ++i) {
        int ch = t + i * 256;
        int r = ch >> 3, c8 = ch & 7;
        *(uint4*)&Qs[r * QSTR + c8 * 8] =
            *(const uint4*)&qb[((size_t)(b * SEQ + qt * 64 + r)) * DMODEL + h * DHEAD + c8 * 8];
    }

    f32x4 O[4];
#pragma unroll
    for (int n0 = 0; n0 < 4; ++n0)
#pragma unroll
        for (int e = 0; e < 4; ++e) O[n0][e] = 0.f;
    float mrow[4] = {-3.4e38f, -3.4e38f, -3.4e38f, -3.4e38f};
    float lrow[4] = {0.f, 0.f, 0.f, 0.f};

    const int qrow = w * 16 + lm;
    const int prow = w * 16 + lq * 4;

    for (int kt = 0; kt < SEQ / 64; ++kt) {
#pragma unroll
        for (int i = 0; i < 2; ++i) {
            int ch = t + i * 256;
            int r = ch >> 3, c8 = ch & 7;
            *(uint4*)&Ks[r * QSTR + c8 * 8] =
                *(const uint4*)&kb[((size_t)(b * SEQ + kt * 64 + r)) * DMODEL + h * DHEAD + c8 * 8];
            *(uint4*)&Vs[r * QSTR + c8 * 8] =
                *(const uint4*)&vtb[(((size_t)(b * NHEAD + h)) * DHEAD + r) * SEQ + kt * 64 + c8 * 8];
        }
        if (t < 64) Ma[t] = (mask[b * SEQ + kt * 64 + t] == 0) ? -1e9f : 0.f;
        __syncthreads();

        bf16x8 aq0 = *(const bf16x8*)&Qs[qrow * QSTR + lq * 8];
        bf16x8 aq1 = *(const bf16x8*)&Qs[qrow * QSTR + lq * 8 + 32];
        f32x4 S[4];
#pragma unroll
        for (int n0 = 0; n0 < 4; ++n0) {
#pragma unroll
            for (int e = 0; e < 4; ++e) S[n0][e] = 0.f;
            bf16x8 b0 = *(const bf16x8*)&Ks[(n0 * 16 + lm) * QSTR + lq * 8];
            bf16x8 b1 = *(const bf16x8*)&Ks[(n0 * 16 + lm) * QSTR + lq * 8 + 32];
            S[n0] = __builtin_amdgcn_mfma_f32_16x16x32_bf16(aq0, b0, S[n0], 0, 0, 0);
            S[n0] = __builtin_amdgcn_mfma_f32_16x16x32_bf16(aq1, b1, S[n0], 0, 0, 0);
        }

        float ma4[4];
#pragma unroll
        for (int n0 = 0; n0 < 4; ++n0) ma4[n0] = Ma[n0 * 16 + lm];
#pragma unroll
        for (int n0 = 0; n0 < 4; ++n0)
#pragma unroll
            for (int r = 0; r < 4; ++r) S[n0][r] += ma4[n0];

        float tm[4];
#pragma unroll
        for (int r = 0; r < 4; ++r)
            tm[r] = fmaxf(fmaxf(S[0][r], S[1][r]), fmaxf(S[2][r], S[3][r]));
#pragma unroll
        for (int off = 1; off < 16; off <<= 1)
#pragma unroll
            for (int r = 0; r < 4; ++r)
                tm[r] = fmaxf(tm[r], __shfl_xor(tm[r], off, 64));

        float al[4], ts[4];
#pragma unroll
        for (int r = 0; r < 4; ++r) {
            float mn = fmaxf(mrow[r], tm[r]);
            al[r] = __expf(mrow[r] - mn);
            mrow[r] = mn;
            ts[r] = 0.f;
        }
#pragma unroll
        for (int n0 = 0; n0 < 4; ++n0)
#pragma unroll
            for (int r = 0; r < 4; ++r) {
                float p = __expf(S[n0][r] - mrow[r]);
                ts[r] += p;
                Ps[(prow + r) * QSTR + n0 * 16 + lm] = f2b(p);
            }
#pragma unroll
        for (int off = 1; off < 16; off <<= 1)
#pragma unroll
            for (int r = 0; r < 4; ++r)
                ts[r] += __shfl_xor(ts[r], off, 64);
#pragma unroll
        for (int r = 0; r < 4; ++r) lrow[r] = lrow[r] * al[r] + ts[r];
#pragma unroll
        for (int n0 = 0; n0 < 4; ++n0)
#pragma unroll
            for (int r = 0; r < 4; ++r) O[n0][r] *= al[r];

        bf16x8 ap0 = *(const bf16x8*)&Ps[qrow * QSTR + lq * 8];
        bf16x8 ap1 = *(const bf16x8*)&Ps[qrow * QSTR + lq * 8 + 32];
#pragma unroll
        for (int n0 = 0; n0 < 4; ++n0) {
            bf16x8 v0 = *(const bf16x8*)&Vs[(n0 * 16 + lm) * QSTR + lq * 8];
            bf16x8 v1 = *(const bf16x8*)&Vs[(n0 * 16 + lm) * QSTR + lq * 8 + 32];
            O[n0] = __builtin_amdgcn_mfma_f32_16x16x32_bf16(ap0, v0, O[n0], 0, 0, 0);
            O[n0] = __builtin_amdgcn_mfma_f32_16x16x32_bf16(ap1, v1, O[n0], 0, 0, 0);
        }
        __syncthreads();
    }

    float inv[4];
#pragma unroll
    for (int r = 0; r < 4; ++r) inv[r] = 1.f / lrow[r];
#pragma unroll
    for (int n0 = 0; n0 < 4; ++n0)
#pragma unroll
        for (int r = 0; r < 4; ++r)
            Ks[(prow + r) * QSTR + n0 * 16 + lm] = f2b(O[n0][r] * inv[r]);
    __syncthreads();
#pragma unroll
    for (int i = 0; i < 2; ++i) {
        int ch = t + i * 256;
        int r = ch >> 3, c8 = ch & 7;
        *(uint4*)&ctxb[((size_t)(b * SEQ + qt * 64 + r)) * DMODEL + h * DHEAD + c8 * 8] =
            *(const uint4*)&Ks[r * QSTR + c8 * 8];
    }
}

// ---------------------------------------------------------------------------
// Per-layer weight transpose+convert: K x N fp32 -> N x K bf16.
// Write path vectorized to ushort2.
// ---------------------------------------------------------------------------
__global__ __launch_bounds__(256) void transpose_w(
    const float* __restrict__ Wq, const float* __restrict__ Wk,
    const float* __restrict__ Wv, const float* __restrict__ Wo,
    const float* __restrict__ W1, const float* __restrict__ W2,
    ushort* __restrict__ Wqt, ushort* __restrict__ Wkt,
    ushort* __restrict__ Wvt, ushort* __restrict__ Wot,
    ushort* __restrict__ W1t, ushort* __restrict__ W2t)
{
    __shared__ float tile[32][33];   // tile[n_local][k_local]
    const int bid = blockIdx.x;
    const float* src; ushort* dst; int K, N, tx, ty;
    if (bid < 2304) {
        int m = bid / 576, tl = bid % 576;
        src = (m == 0) ? Wq : (m == 1) ? Wk : (m == 2) ? Wv : Wo;
        dst = (m == 0) ? Wqt : (m == 1) ? Wkt : (m == 2) ? Wvt : Wot;
        K = 768; N = 768; tx = tl % 24; ty = tl / 24;
    } else if (bid < 4608) {
        int tl = bid - 2304;
        src = W1; dst = W1t; K = 768; N = 3072; tx = tl % 96; ty = tl / 96;
    } else {
        int tl = bid - 4608;
        src = W2; dst = W2t; K = 3072; N = 768; tx = tl % 24; ty = tl / 24;
    }
    const int t = threadIdx.x;
    const int lx = t & 31, ly = t >> 5;
    const int n0 = tx * 32, k0 = ty * 32;
#pragma unroll
    for (int i = 0; i < 4; ++i)
        tile[lx][ly + i * 8] = src[(size_t)(k0 + ly + i * 8) * N + n0 + lx];
    __syncthreads();
    const int kk2 = (t & 15) * 2, nn = t >> 4;   // 2 k's, 16 n-slots
#pragma unroll
    for (int i = 0; i < 2; ++i) {
        int nl = nn + i * 16;
        ushort2 o;
        o.x = f2b(tile[nl][kk2]);
        o.y = f2b(tile[nl][kk2 + 1]);
        *(ushort2*)&dst[(size_t)(n0 + nl) * K + k0 + kk2] = o;
    }
}

// ---------------------------------------------------------------------------
// init: hbuf = x (fp32 copy), hb = bf16(x).
// ---------------------------------------------------------------------------
__global__ __launch_bounds__(256) void init_kernel(
    const float* __restrict__ x, float* __restrict__ hbuf,
    ushort* __restrict__ hb)
{
    const size_t i = ((size_t)blockIdx.x * 256 + threadIdx.x) * 4;
    float4 v = *(const float4*)(x + i);
    *(float4*)(hbuf + i) = v;
    ushort4 o;
    o.x = f2b(v.x); o.y = f2b(v.y); o.z = f2b(v.z); o.w = f2b(v.w);
    *(ushort4*)(hb + i) = o;
}

// ---------------------------------------------------------------------------
// out = LayerNorm(p0 + p1 + res); fp32 out + bf16 shadow.
// float4-vectorized (G13): 192 threads, one float4 per array per thread.
// ---------------------------------------------------------------------------
__global__ __launch_bounds__(192) void add_ln3_kernel(
    const float* __restrict__ p0, const float* __restrict__ p1,
    const float* __restrict__ res,
    const float* __restrict__ gw, const float* __restrict__ bw,
    float* __restrict__ out, ushort* __restrict__ outb)
{
    const int row = blockIdx.x;
    const int t = threadIdx.x;           // 0..191 (192*4 = 768)
    __shared__ float red[6];

    const float4 v0 = ((const float4*)(p0 + (size_t)row * DMODEL))[t];
    const float4 v1 = ((const float4*)(p1 + (size_t)row * DMODEL))[t];
    const float4 v2 = ((const float4*)(res + (size_t)row * DMODEL))[t];

    float4 vv;
    vv.x = v0.x + v1.x + v2.x;
    vv.y = v0.y + v1.y + v2.y;
    vv.z = v0.z + v1.z + v2.z;
    vv.w = v0.w + v1.w + v2.w;

    float s = (vv.x + vv.y) + (vv.z + vv.w);
#pragma unroll
    for (int off = 32; off > 0; off >>= 1) s += __shfl_down(s, off, 64);
    if ((t & 63) == 0) red[t >> 6] = s;
    __syncthreads();
    const float mu = (red[0] + red[1] + red[2]) * (1.0f / DMODEL);

    float dx = vv.x - mu, dy = vv.y - mu, dz = vv.z - mu, dw = vv.w - mu;
    float vs = (dx * dx + dy * dy) + (dz * dz + dw * dw);
#pragma unroll
    for (int off = 32; off > 0; off >>= 1) vs += __shfl_down(vs, off, 64);
    if ((t & 63) == 0) red[3 + (t >> 6)] = vs;
    __syncthreads();
    const float var = (red[3] + red[4] + red[5]) * (1.0f / DMODEL);
    const float inv = rsqrtf(var + 1e-12f);

    const float4 g = ((const float4*)gw)[t];
    const float4 bb = ((const float4*)bw)[t];
    float4 o;
    o.x = dx * inv * g.x + bb.x;
    o.y = dy * inv * g.y + bb.y;
    o.z = dz * inv * g.z + bb.z;
    o.w = dw * inv * g.w + bb.w;
    ((float4*)(out + (size_t)row * DMODEL))[t] = o;
    ushort4 ob;
    ob.x = f2b(o.x); ob.y = f2b(o.y); ob.z = f2b(o.z); ob.w = f2b(o.w);
    ((ushort4*)(outb + (size_t)row * DMODEL))[t] = ob;
}

// ---------------------------------------------------------------------------
extern "C" void kernel_launch(void* const* d_in, const int* in_sizes, int n_in,
                              void* d_out, int out_size, void* d_ws, size_t ws_size,
                              hipStream_t stream)
{
    const float* x    = (const float*)d_in[0];
    const int*   mask = (const int*)d_in[1];
    const float* Wq = (const float*)d_in[2];
    const float* bq = (const float*)d_in[3];
    const float* Wk = (const float*)d_in[4];
    const float* bk = (const float*)d_in[5];
    const float* Wv = (const float*)d_in[6];
    const float* bv = (const float*)d_in[7];
    const float* Wo = (const float*)d_in[8];
    const float* bo = (const float*)d_in[9];
    const float* ln1g = (const float*)d_in[10];
    const float* ln1b = (const float*)d_in[11];
    const float* W1 = (const float*)d_in[12];
    const float* b1 = (const float*)d_in[13];
    const float* W2 = (const float*)d_in[14];
    const float* b2 = (const float*)d_in[15];
    const float* ln2g = (const float*)d_in[16];
    const float* ln2b = (const float*)d_in[17];

    // ---- workspace layout (~102 MB) ----
    float* f32b = (float*)d_ws;
    float* hbuf = f32b;            // h residual (fp32)
    float* f1   = f32b + ND;       // split-K partial 0
    float* h2   = f32b + 2 * ND;   // h2 residual (fp32)
    ushort* ub  = (ushort*)(f32b + 3 * ND);
    ushort* qb  = ub;                          // q bf16 (scaled)
    ushort* kb  = ub + ND;                     // k bf16
    ushort* vtb = ub + 2 * ND;                 // v^T bf16 [b,h,d,s]
    ushort* hb  = ub + 3 * ND;                 // h bf16
    ushort* U   = ub + 4 * ND;                 // gelu-out bf16 (NTOK x FF)
    ushort* ctxb = U;                          // ctx bf16 (aliases U; disjoint lifetime)
    ushort* Wqkvt = U + (size_t)NTOK * FFDIM;  // 2304 x 768 contiguous
    ushort* Wot = Wqkvt + 3 * 768 * 768;
    ushort* W1t = Wot + 768 * 768;             // 3072 x 768
    ushort* W2t = W1t + (size_t)768 * 3072;    // 768 x 3072

    // split-K partial 1: ND floats overlaying qb+kb (dead when sk-GEMMs run;
    // rewritten by the NEXT layer's gemm_qkv only after add_ln3 consumed p1)
    float* p1 = (float*)ub;

    init_kernel<<<(int)(ND / 1024), 256, 0, stream>>>(x, hbuf, hb);

    const dim3 gQKV(18, 64);        // N=2304, 64x128, BK=64
    const dim3 gSK(6, 64, 2);       // N=768, 64x128, BK=64, split-K=2
    const dim3 gFF(24, 32);         // N=3072, 128x128, BK=32
    const dim3 gA(SEQ / 64, NHEAD, BATCH);

    for (int l = 0; l < NLAYER; ++l) {
        const float* Wq_l = Wq + (size_t)l * DMODEL * DMODEL;
        const float* Wk_l = Wk + (size_t)l * DMODEL * DMODEL;
        const float* Wv_l = Wv + (size_t)l * DMODEL * DMODEL;
        const float* Wo_l = Wo + (size_t)l * DMODEL * DMODEL;
        const float* W1_l = W1 + (size_t)l * DMODEL * FFDIM;
        const float* W2_l = W2 + (size_t)l * FFDIM * DMODEL;

        transpose_w<<<6912, 256, 0, stream>>>(Wq_l, Wk_l, Wv_l, Wo_l, W1_l, W2_l,
                                              Wqkvt, Wqkvt + 768 * 768,
                                              Wqkvt + 2 * 768 * 768, Wot, W1t, W2t);

        gemm_qkv<<<gQKV, 256, 0, stream>>>(hb, Wqkvt,
                                           bq + (size_t)l * DMODEL,
                                           bk + (size_t)l * DMODEL,
                                           bv + (size_t)l * DMODEL,
                                           qb, kb, vtb);

        attn_mfma<<<gA, 256, 0, stream>>>(qb, kb, vtb, mask, ctxb);

        // sa = ctx @ Wo + bo, split-K=2 -> partials f1 (z=0) and p1 (z=1)
        gemm_mfma_sk<<<gSK, 256, 0, stream>>>(ctxb, Wot, bo + (size_t)l * DMODEL,
                                              f1, p1, NTOK, DMODEL, DMODEL, DMODEL / 2);

        // h2 = LN(f1 + p1 + h)
        add_ln3_kernel<<<NTOK, 192, 0, stream>>>(f1, p1, hbuf,
                                                 ln1g + (size_t)l * DMODEL,
                                                 ln1b + (size_t)l * DMODEL, h2, hb);

        gemm_mfma<<<gFF, 256, 0, stream>>>(hb, W1t, b1 + (size_t)l * FFDIM,
                                           nullptr, U, NTOK, DMODEL, FFDIM, 1);

        // ffn_out = U @ W2 + b2, split-K=2
        gemm_mfma_sk<<<gSK, 256, 0, stream>>>(U, W2t, b2 + (size_t)l * DMODEL,
                                              f1, p1, NTOK, FFDIM, DMODEL, FFDIM / 2);

        // h = LN(f1 + p1 + h2); last layer -> d_out
        float* hout = (l == NLAYER - 1) ? (float*)d_out : hbuf;
        add_ln3_kernel<<<NTOK, 192, 0, stream>>>(f1, p1, h2,
                                                 ln2g + (size_t)l * DMODEL,
                                                 ln2b + (size_t)l * DMODEL, hout, hb);
    }
}